// Round 5
// baseline (1149.671 us; speedup 1.0000x reference)
//
#include <hip/hip_runtime.h>

// ---------------- constants ----------------
#define Bb 8
#define Tt 512
#define Cc 1024
#define Hh 16
#define Nh 64
#define Mm 4096            // B*T
#define BTC 4194304        // M*C
#define DEV __device__ __forceinline__

typedef __attribute__((ext_vector_type(8))) short short8;
typedef __attribute__((ext_vector_type(4))) float f32x4;

DEV unsigned short f2bf(float f) {
  unsigned int u = __builtin_bit_cast(unsigned int, f);
  u += 0x7fffu + ((u >> 16) & 1u);
  return (unsigned short)(u >> 16);
}

// ---------------- transpose f32 (K x N) -> bf16 (N x K) ----------------
__global__ __launch_bounds__(256) void kt_transpose(const float* __restrict__ in,
                                                    unsigned short* __restrict__ out,
                                                    int K, int N) {
  __shared__ float tile[32][33];
  int bx = blockIdx.x * 32;  // n
  int by = blockIdx.y * 32;  // k
  int tx = threadIdx.x, ty = threadIdx.y;
  #pragma unroll
  for (int i = ty; i < 32; i += 8) {
    int kk = by + i, nn = bx + tx;
    tile[i][tx] = (kk < K && nn < N) ? in[(size_t)kk * N + nn] : 0.f;
  }
  __syncthreads();
  #pragma unroll
  for (int i = ty; i < 32; i += 8) {
    int nn = bx + i, kk = by + tx;
    if (nn < N && kk < K) out[(size_t)nn * K + kk] = f2bf(tile[tx][i]);
  }
}

// ---------------- block row stats (1024 elems over 256 threads) ----------------
DEV void row_stats(float v0, float v1, float v2, float v3, float* red,
                   float& mu, float& rs, float eps) {
  float s = v0 + v1 + v2 + v3;
  float q = v0 * v0 + v1 * v1 + v2 * v2 + v3 * v3;
  #pragma unroll
  for (int o = 32; o; o >>= 1) { s += __shfl_down(s, o); q += __shfl_down(q, o); }
  int w = threadIdx.x >> 6;
  __syncthreads();
  if ((threadIdx.x & 63) == 0) { red[w] = s; red[4 + w] = q; }
  __syncthreads();
  s = red[0] + red[1] + red[2] + red[3];
  q = red[4] + red[5] + red[6] + red[7];
  mu = s * (1.f / 1024.f);
  float var = q * (1.f / 1024.f) - mu * mu;
  rs = rsqrtf(var + eps);
}

// ---------------- K1: pre-LN + attn-LN + time-shift mixes ----------------
__global__ __launch_bounds__(256) void k1_mix(
    const float* __restrict__ x,
    const float* __restrict__ lnpw, const float* __restrict__ lnpb,
    const float* __restrict__ lnaw, const float* __restrict__ lnab,
    const float* __restrict__ cr, const float* __restrict__ cw,
    const float* __restrict__ ck, const float* __restrict__ cv,
    const float* __restrict__ ca, const float* __restrict__ cg,
    float* __restrict__ xln,
    unsigned short* __restrict__ mR, unsigned short* __restrict__ mW,
    unsigned short* __restrict__ mK, unsigned short* __restrict__ mV,
    unsigned short* __restrict__ mA, unsigned short* __restrict__ mG) {
  __shared__ float red[8];
  const int row = blockIdx.x;
  const int t = row & (Tt - 1);
  const int tid = threadIdx.x;
  const int c = tid * 4;
  const size_t base = (size_t)row * Cc + c;
  float a0 = x[base], a1 = x[base + 1], a2 = x[base + 2], a3 = x[base + 3];
  float mu, rs;
  row_stats(a0, a1, a2, a3, red, mu, rs, 1e-5f);
  float pw0 = lnpw[c], pw1 = lnpw[c + 1], pw2 = lnpw[c + 2], pw3 = lnpw[c + 3];
  float pb0 = lnpb[c], pb1 = lnpb[c + 1], pb2 = lnpb[c + 2], pb3 = lnpb[c + 3];
  float l0 = (a0 - mu) * rs * pw0 + pb0, l1 = (a1 - mu) * rs * pw1 + pb1;
  float l2 = (a2 - mu) * rs * pw2 + pb2, l3 = (a3 - mu) * rs * pw3 + pb3;
  float4 st; st.x = l0; st.y = l1; st.z = l2; st.w = l3;
  *(float4*)(xln + base) = st;
  row_stats(l0, l1, l2, l3, red, mu, rs, 1e-5f);
  float aw0 = lnaw[c], aw1 = lnaw[c + 1], aw2 = lnaw[c + 2], aw3 = lnaw[c + 3];
  float ab0 = lnab[c], ab1 = lnab[c + 1], ab2 = lnab[c + 2], ab3 = lnab[c + 3];
  float n0 = (l0 - mu) * rs * aw0 + ab0, n1 = (l1 - mu) * rs * aw1 + ab1;
  float n2 = (l2 - mu) * rs * aw2 + ab2, n3 = (l3 - mu) * rs * aw3 + ab3;
  float p0 = 0.f, p1 = 0.f, p2 = 0.f, p3 = 0.f;
  if (t > 0) {  // uniform over block
    const size_t pb_ = base - Cc;
    float q0 = x[pb_], q1 = x[pb_ + 1], q2 = x[pb_ + 2], q3 = x[pb_ + 3];
    row_stats(q0, q1, q2, q3, red, mu, rs, 1e-5f);
    float e0 = (q0 - mu) * rs * pw0 + pb0, e1 = (q1 - mu) * rs * pw1 + pb1;
    float e2 = (q2 - mu) * rs * pw2 + pb2, e3 = (q3 - mu) * rs * pw3 + pb3;
    row_stats(e0, e1, e2, e3, red, mu, rs, 1e-5f);
    p0 = (e0 - mu) * rs * aw0 + ab0; p1 = (e1 - mu) * rs * aw1 + ab1;
    p2 = (e2 - mu) * rs * aw2 + ab2; p3 = (e3 - mu) * rs * aw3 + ab3;
  }
  float d0 = p0 - n0, d1 = p1 - n1, d2 = p2 - n2, d3 = p3 - n3;
  #define EMIT(cf, dst) { \
    float f0 = cf[c], f1 = cf[c + 1], f2 = cf[c + 2], f3 = cf[c + 3]; \
    ushort4 u; u.x = f2bf(n0 + d0 * f0); u.y = f2bf(n1 + d1 * f1); \
    u.z = f2bf(n2 + d2 * f2); u.w = f2bf(n3 + d3 * f3); \
    *(ushort4*)(dst + base) = u; }
  EMIT(cr, mR) EMIT(cw, mW) EMIT(ck, mK) EMIT(cv, mV) EMIT(ca, mA) EMIT(cg, mG)
  #undef EMIT
}

// ---------------- generic 128x128x32 bf16 MFMA GEMM ----------------
// A: (M,K) bf16 row-major; Bt: (N,K) bf16 row-major (i.e. B transposed)
// MODE: 0 f32 | 1 bf16 | 2 tanh->bf16 | 3 sigmoid->bf16 | 4 relu^2->bf16
//       5 sigmoid(z+bias[col])->f32 | 6 exp(-sigmoid(z+bias[col])*e^-.5)->f32 | 7 z+res->f32
template <int MODE>
__global__ __launch_bounds__(256) void kg_gemm(
    const unsigned short* __restrict__ A, const unsigned short* __restrict__ Bt,
    int M, int Nn, int K,
    float* __restrict__ outF, unsigned short* __restrict__ outB,
    const float* __restrict__ bias, const float* __restrict__ res) {
  constexpr int PAD = 40;
  __shared__ unsigned short lsA[128 * PAD];
  __shared__ unsigned short lsB[128 * PAD];
  const int tid = threadIdx.x;
  const int lane = tid & 63;
  const int wave = tid >> 6;
  const int wy = wave >> 1, wx = wave & 1;
  const int m0 = blockIdx.y * 128;
  const int n0 = blockIdx.x * 128;
  const int sr = tid >> 2;          // staging row 0..63
  const int sk = (tid & 3) << 3;    // staging k-offset (elems)
  f32x4 acc[4][4];
  #pragma unroll
  for (int i = 0; i < 4; ++i)
    #pragma unroll
    for (int j = 0; j < 4; ++j) { f32x4 z = {0.f, 0.f, 0.f, 0.f}; acc[i][j] = z; }
  const int fr = lane & 15;
  const int fk = (lane >> 4) << 3;
  for (int k0 = 0; k0 < K; k0 += 32) {
    uint4 av0 = *(const uint4*)(A + (size_t)(m0 + sr) * K + k0 + sk);
    uint4 av1 = *(const uint4*)(A + (size_t)(m0 + sr + 64) * K + k0 + sk);
    uint4 bv0 = {0u, 0u, 0u, 0u}, bv1 = {0u, 0u, 0u, 0u};
    if (n0 + sr < Nn)      bv0 = *(const uint4*)(Bt + (size_t)(n0 + sr) * K + k0 + sk);
    if (n0 + sr + 64 < Nn) bv1 = *(const uint4*)(Bt + (size_t)(n0 + sr + 64) * K + k0 + sk);
    __syncthreads();
    *(uint4*)(lsA + sr * PAD + sk) = av0;
    *(uint4*)(lsA + (sr + 64) * PAD + sk) = av1;
    *(uint4*)(lsB + sr * PAD + sk) = bv0;
    *(uint4*)(lsB + (sr + 64) * PAD + sk) = bv1;
    __syncthreads();
    short8 af[4], bf[4];
    #pragma unroll
    for (int mt = 0; mt < 4; ++mt)
      af[mt] = *(const short8*)(lsA + (wy * 64 + mt * 16 + fr) * PAD + fk);
    #pragma unroll
    for (int nt = 0; nt < 4; ++nt)
      bf[nt] = *(const short8*)(lsB + (wx * 64 + nt * 16 + fr) * PAD + fk);
    #pragma unroll
    for (int mt = 0; mt < 4; ++mt)
      #pragma unroll
      for (int nt = 0; nt < 4; ++nt)
        acc[mt][nt] = __builtin_amdgcn_mfma_f32_16x16x32_bf16(af[mt], bf[nt], acc[mt][nt], 0, 0, 0);
  }
  const int rbase = (lane >> 4) << 2;
  const int cbase = lane & 15;
  #pragma unroll
  for (int mt = 0; mt < 4; ++mt)
    #pragma unroll
    for (int nt = 0; nt < 4; ++nt)
      #pragma unroll
      for (int rr = 0; rr < 4; ++rr) {
        int row = m0 + wy * 64 + mt * 16 + rbase + rr;
        int col = n0 + wx * 64 + nt * 16 + cbase;
        if (col < Nn) {
          size_t oi = (size_t)row * Nn + col;
          float z = acc[mt][nt][rr];
          if constexpr (MODE == 0) outF[oi] = z;
          else if constexpr (MODE == 1) outB[oi] = f2bf(z);
          else if constexpr (MODE == 2) outB[oi] = f2bf(tanhf(z));
          else if constexpr (MODE == 3) outB[oi] = f2bf(1.f / (1.f + expf(-z)));
          else if constexpr (MODE == 4) { float m = fmaxf(z, 0.f); outB[oi] = f2bf(m * m); }
          else if constexpr (MODE == 5) { z += bias[col]; outF[oi] = 1.f / (1.f + expf(-z)); }
          else if constexpr (MODE == 6) {
            z += bias[col];
            float sg = 1.f / (1.f + expf(-z));
            outF[oi] = expf(-0.6065306597126334f * sg);
          } else { outF[oi] = z + res[oi]; }
        }
      }
}

// ---------------- K4: kk-normalize, a/b vectors, k update (in place) ----------------
__global__ __launch_bounds__(256) void k4_prep(
    float* __restrict__ k, const float* __restrict__ a,
    const float* __restrict__ kkc, const float* __restrict__ kac,
    float* __restrict__ aw, float* __restrict__ bw) {
  const int row = blockIdx.x, tid = threadIdx.x;
  const int c = tid * 4;
  const size_t base = (size_t)row * Cc + c;
  float k0 = k[base], k1 = k[base + 1], k2 = k[base + 2], k3 = k[base + 3];
  float a0 = a[base], a1 = a[base + 1], a2 = a[base + 2], a3 = a[base + 3];
  float h0 = k0 * kkc[c], h1 = k1 * kkc[c + 1], h2 = k2 * kkc[c + 2], h3 = k3 * kkc[c + 3];
  float ss = h0 * h0 + h1 * h1 + h2 * h2 + h3 * h3;
  #pragma unroll
  for (int m = 8; m; m >>= 1) ss += __shfl_xor(ss, m);
  float inv = 1.f / fmaxf(sqrtf(ss), 1e-12f);
  h0 *= inv; h1 *= inv; h2 *= inv; h3 *= inv;
  float4 v4;
  v4.x = -h0; v4.y = -h1; v4.z = -h2; v4.w = -h3;
  *(float4*)(aw + base) = v4;
  v4.x = h0 * a0; v4.y = h1 * a1; v4.z = h2 * a2; v4.w = h3 * a3;
  *(float4*)(bw + base) = v4;
  v4.x = k0 * (1.f + (a0 - 1.f) * kac[c]);
  v4.y = k1 * (1.f + (a1 - 1.f) * kac[c + 1]);
  v4.z = k2 * (1.f + (a2 - 1.f) * kac[c + 2]);
  v4.w = k3 * (1.f + (a3 - 1.f) * kac[c + 3]);
  *(float4*)(k + base) = v4;
}

// ---------------- K5: WKV7 recurrence — chunked LDS staging ----------------
// 256 blocks = (b,h,rowhalf); 1 wave; lane = 32 rows x 2 col-halves; S in 32 VGPRs.
// T processed in chunks of CS=16 steps. A whole chunk of operands (6 arrays x
// 16 steps x 64 floats = 24 KB) is prefetched into 24 uint4 REGISTERS one full
// chunk ahead (~8000 cyc slack >> 900-cyc HBM latency; straight-line code, no
// conditionals for the waitcnt pass to merge conservatively — the R2-R4
// pathology), then ds_written to a double-buffered LDS chunk at chunk start.
// The 16-step compute loop touches LDS only (precise lgkm waits).
#define CS 16
__global__ __launch_bounds__(64) void k5_wkv7(
    const float* __restrict__ r, const float* __restrict__ dec,
    const float* __restrict__ k, const float* __restrict__ v,
    const float* __restrict__ aw, const float* __restrict__ bw,
    float* __restrict__ o) {
  const int blk = blockIdx.x;          // 0..255
  const int bh = blk >> 1, half = blk & 1;
  const int b = bh >> 4, h = bh & 15;
  const int lane = threadIdx.x;
  const int r2 = lane & 31;            // row within half
  const int ch = lane >> 5;            // column half (0/1)
  const int row = half * 32 + r2;      // state row i
  const int cb = ch << 5;              // column base j0

  // buf layout per chunk: arr-major [6][CS][64] floats; arrs: a,d,b,k,r,v
  __shared__ float buf[2][6 * CS * 64];

  float S[32];
  #pragma unroll
  for (int j = 0; j < 32; ++j) S[j] = 0.f;

  const size_t base = (size_t)b * Tt * Cc + (size_t)h * Nh;
  // staging: instr (arr,sg): 64 lanes cover 4 consecutive steps x 256B of arr.
  // global float offset = base + (cstart + sg*4 + (lane>>4))*Cc + (lane&15)*4
  // LDS float offset    = arr*(CS*64) + sg*256 + lane*4      (identical order)
  const int loff = ((lane >> 4) << 10) + ((lane & 15) << 2);
  const int soff = lane << 2;

  uint4 R[24];
  #define LOADC(cstart) { \
    const size_t g0 = base + (size_t)(cstart) * Cc + loff; \
    _Pragma("unroll") \
    for (int sg = 0; sg < 4; ++sg) { \
      R[0 * 4 + sg] = *(const uint4*)(aw  + g0 + sg * 4096); \
      R[1 * 4 + sg] = *(const uint4*)(dec + g0 + sg * 4096); \
      R[2 * 4 + sg] = *(const uint4*)(bw  + g0 + sg * 4096); \
      R[3 * 4 + sg] = *(const uint4*)(k   + g0 + sg * 4096); \
      R[4 * 4 + sg] = *(const uint4*)(r   + g0 + sg * 4096); \
      R[5 * 4 + sg] = *(const uint4*)(v   + g0 + sg * 4096); \
    } }

  LOADC(0)

  #pragma unroll 1
  for (int c = 0; c < Tt / CS; ++c) {
    float* bp = buf[c & 1];
    // commit chunk c (regs loaded one chunk ago -> huge vmcnt slack)
    #pragma unroll
    for (int arr = 0; arr < 6; ++arr)
      #pragma unroll
      for (int sg = 0; sg < 4; ++sg)
        *(uint4*)(bp + arr * (CS * 64) + sg * 256 + soff) = R[arr * 4 + sg];
    // issue chunk c+1 loads (clamped, branchless)
    const int cn = (c + 1 < Tt / CS) ? (c + 1) : c;
    LOADC(cn * CS)
    // compute CS steps from LDS only
    #pragma unroll 1
    for (int s = 0; s < CS; ++s) {
      const int t = c * CS + s;
      const float* sp = bp + s * 64;
      const float* ap  = sp + cb;
      const float* dp  = sp + 1 * (CS * 64) + cb;
      const float* bpp = sp + 2 * (CS * 64) + cb;
      const float* kp  = sp + 3 * (CS * 64) + cb;
      const float* rp  = sp + 4 * (CS * 64) + cb;
      const float  vv  = sp[5 * (CS * 64) + row];

      float sa0 = 0.f, sa1 = 0.f, sa2 = 0.f, sa3 = 0.f;
      #pragma unroll
      for (int jj = 0; jj < 32; jj += 4) {
        float4 a4 = *(const float4*)(ap + jj);
        sa0 = fmaf(S[jj + 0], a4.x, sa0);
        sa1 = fmaf(S[jj + 1], a4.y, sa1);
        sa2 = fmaf(S[jj + 2], a4.z, sa2);
        sa3 = fmaf(S[jj + 3], a4.w, sa3);
      }
      float sa = (sa0 + sa1) + (sa2 + sa3);
      sa += __shfl_xor(sa, 32);

      float o0 = 0.f, o1 = 0.f, o2 = 0.f, o3 = 0.f;
      #pragma unroll
      for (int jj = 0; jj < 32; jj += 4) {
        float4 d4 = *(const float4*)(dp + jj);
        float4 b4 = *(const float4*)(bpp + jj);
        float4 k4 = *(const float4*)(kp + jj);
        float4 r4 = *(const float4*)(rp + jj);
        S[jj + 0] = fmaf(S[jj + 0], d4.x, fmaf(vv, k4.x, sa * b4.x));
        o0 = fmaf(S[jj + 0], r4.x, o0);
        S[jj + 1] = fmaf(S[jj + 1], d4.y, fmaf(vv, k4.y, sa * b4.y));
        o1 = fmaf(S[jj + 1], r4.y, o1);
        S[jj + 2] = fmaf(S[jj + 2], d4.z, fmaf(vv, k4.z, sa * b4.z));
        o2 = fmaf(S[jj + 2], r4.z, o2);
        S[jj + 3] = fmaf(S[jj + 3], d4.w, fmaf(vv, k4.w, sa * b4.w));
        o3 = fmaf(S[jj + 3], r4.w, o3);
      }
      float oo = (o0 + o1) + (o2 + o3);
      oo += __shfl_xor(oo, 32);
      if (ch == 0) o[base + (size_t)t * Cc + row] = oo;
    }
  }
  #undef LOADC
}

// ---------------- K6: head GroupNorm + rk bonus + gate ----------------
__global__ __launch_bounds__(256) void k6_out(
    const float* __restrict__ o, const float* __restrict__ r, const float* __restrict__ k,
    const float* __restrict__ v, const float* __restrict__ rk,
    const float* __restrict__ gnw, const float* __restrict__ gnb,
    const float* __restrict__ g, unsigned short* __restrict__ og) {
  const int row = blockIdx.x, tid = threadIdx.x;
  const int c = tid * 4;
  const size_t base = (size_t)row * Cc + c;
  float o0 = o[base], o1 = o[base + 1], o2 = o[base + 2], o3 = o[base + 3];
  float r0 = r[base], r1 = r[base + 1], r2 = r[base + 2], r3 = r[base + 3];
  float k0 = k[base], k1 = k[base + 1], k2 = k[base + 2], k3 = k[base + 3];
  float s = o0 + o1 + o2 + o3;
  float q = o0 * o0 + o1 * o1 + o2 * o2 + o3 * o3;
  float bs = r0 * k0 * rk[c] + r1 * k1 * rk[c + 1] + r2 * k2 * rk[c + 2] + r3 * k3 * rk[c + 3];
  #pragma unroll
  for (int m = 8; m; m >>= 1) {
    s += __shfl_xor(s, m); q += __shfl_xor(q, m); bs += __shfl_xor(bs, m);
  }
  float mu = s * (1.f / 64.f);
  float var = q * (1.f / 64.f) - mu * mu;
  float rs = rsqrtf(var + 64e-5f);
  float v0 = v[base], v1 = v[base + 1], v2 = v[base + 2], v3 = v[base + 3];
  float z0 = (o0 - mu) * rs * gnw[c] + gnb[c] + bs * v0;
  float z1 = (o1 - mu) * rs * gnw[c + 1] + gnb[c + 1] + bs * v1;
  float z2 = (o2 - mu) * rs * gnw[c + 2] + gnb[c + 2] + bs * v2;
  float z3 = (o3 - mu) * rs * gnw[c + 3] + gnb[c + 3] + bs * v3;
  ushort4 u;
  u.x = f2bf(z0 * g[base]); u.y = f2bf(z1 * g[base + 1]);
  u.z = f2bf(z2 * g[base + 2]); u.w = f2bf(z3 * g[base + 3]);
  *(ushort4*)(og + base) = u;
}

// ---------------- K8: FFN LN + time-shift mix ----------------
__global__ __launch_bounds__(256) void k8_ffnmix(
    const float* __restrict__ x2, const float* __restrict__ lnw, const float* __restrict__ lnb,
    const float* __restrict__ fxk, unsigned short* __restrict__ kf) {
  __shared__ float red[8];
  const int row = blockIdx.x;
  const int t = row & (Tt - 1);
  const int tid = threadIdx.x;
  const int c = tid * 4;
  const size_t base = (size_t)row * Cc + c;
  float a0 = x2[base], a1 = x2[base + 1], a2 = x2[base + 2], a3 = x2[base + 3];
  float mu, rs;
  row_stats(a0, a1, a2, a3, red, mu, rs, 1e-5f);
  float w0 = lnw[c], w1 = lnw[c + 1], w2 = lnw[c + 2], w3 = lnw[c + 3];
  float b0 = lnb[c], b1 = lnb[c + 1], b2 = lnb[c + 2], b3 = lnb[c + 3];
  float f0 = (a0 - mu) * rs * w0 + b0, f1 = (a1 - mu) * rs * w1 + b1;
  float f2 = (a2 - mu) * rs * w2 + b2, f3 = (a3 - mu) * rs * w3 + b3;
  float p0 = 0.f, p1 = 0.f, p2 = 0.f, p3 = 0.f;
  if (t > 0) {
    const size_t pb_ = base - Cc;
    float q0 = x2[pb_], q1 = x2[pb_ + 1], q2 = x2[pb_ + 2], q3 = x2[pb_ + 3];
    row_stats(q0, q1, q2, q3, red, mu, rs, 1e-5f);
    p0 = (q0 - mu) * rs * w0 + b0; p1 = (q1 - mu) * rs * w1 + b1;
    p2 = (q2 - mu) * rs * w2 + b2; p3 = (q3 - mu) * rs * w3 + b3;
  }
  ushort4 u;
  u.x = f2bf(f0 + (p0 - f0) * fxk[c]);
  u.y = f2bf(f1 + (p1 - f1) * fxk[c + 1]);
  u.z = f2bf(f2 + (p2 - f2) * fxk[c + 2]);
  u.w = f2bf(f3 + (p3 - f3) * fxk[c + 3]);
  *(ushort4*)(kf + base) = u;
}

// ---------------- host ----------------
extern "C" void kernel_launch(void* const* d_in, const int* in_sizes, int n_in,
                              void* d_out, int out_size, void* d_ws, size_t ws_size,
                              hipStream_t stream) {
  (void)in_sizes; (void)n_in; (void)out_size; (void)ws_size;
  const float* x    = (const float*)d_in[0];
  const float* lnpw = (const float*)d_in[2];
  const float* lnpb = (const float*)d_in[3];
  const float* lnaw = (const float*)d_in[4];
  const float* lnab = (const float*)d_in[5];
  const float* lnfw = (const float*)d_in[6];
  const float* lnfb = (const float*)d_in[7];
  const float* cxr  = (const float*)d_in[8];
  const float* cxw  = (const float*)d_in[9];
  const float* cxk  = (const float*)d_in[10];
  const float* cxv  = (const float*)d_in[11];
  const float* cxa  = (const float*)d_in[12];
  const float* cxg  = (const float*)d_in[13];
  const float* w0v  = (const float*)d_in[14];
  const float* w1m  = (const float*)d_in[15];
  const float* w2m  = (const float*)d_in[16];
  const float* a0v  = (const float*)d_in[17];
  const float* a1m  = (const float*)d_in[18];
  const float* a2m  = (const float*)d_in[19];
  const float* g1m  = (const float*)d_in[20];
  const float* g2m  = (const float*)d_in[21];
  const float* kkv  = (const float*)d_in[22];
  const float* kav  = (const float*)d_in[23];
  const float* rkv  = (const float*)d_in[24];
  const float* Wr   = (const float*)d_in[25];
  const float* Wk   = (const float*)d_in[26];
  const float* Wv   = (const float*)d_in[27];
  const float* Wo   = (const float*)d_in[28];
  const float* gnw  = (const float*)d_in[29];
  const float* gnb  = (const float*)d_in[30];
  const float* fxk  = (const float*)d_in[31];
  const float* Wf1  = (const float*)d_in[32];
  const float* Wf2  = (const float*)d_in[33];

  char* ws = (char*)d_ws;
  float* outx = (float*)d_out;          // final x (B,T,C)
  float* vout = outx + BTC;             // v_first = v (B,T,C)

  // workspace layout (all offsets multiples of big pow2; aliases noted)
  size_t off = 0;
  unsigned short* WrT  = (unsigned short*)(ws + off); off += 2097152;
  unsigned short* WkT  = (unsigned short*)(ws + off); off += 2097152;
  unsigned short* WvT  = (unsigned short*)(ws + off); off += 2097152;
  unsigned short* WoT  = (unsigned short*)(ws + off); off += 2097152;
  unsigned short* Wf1T = (unsigned short*)(ws + off); off += 8388608;
  unsigned short* Wf2T = (unsigned short*)(ws + off); off += 8388608;
  unsigned short* w1T  = (unsigned short*)(ws + off); off += 131072;
  unsigned short* w2T  = (unsigned short*)(ws + off); off += 131072;
  unsigned short* a1T  = (unsigned short*)(ws + off); off += 131072;
  unsigned short* a2T  = (unsigned short*)(ws + off); off += 131072;
  unsigned short* g1T  = (unsigned short*)(ws + off); off += 262144;
  unsigned short* g2T  = (unsigned short*)(ws + off); off += 262144;
  float* xln = (float*)(ws + off); off += 16777216;
  unsigned short* mixR = (unsigned short*)(ws + off);          // 6 x 8388608
  unsigned short* mixW = (unsigned short*)(ws + off + 8388608);
  unsigned short* mixK = (unsigned short*)(ws + off + 16777216);
  unsigned short* mixV = (unsigned short*)(ws + off + 25165824);
  unsigned short* mixA = (unsigned short*)(ws + off + 33554432);
  unsigned short* mixG = (unsigned short*)(ws + off + 41943040);
  unsigned short* hbuf = (unsigned short*)(ws + off);          // alias mix (dead by then)
  off += 50331648;
  unsigned short* tmpw = (unsigned short*)(ws + off); off += 524288;
  unsigned short* tmpa = (unsigned short*)(ws + off); off += 524288;
  unsigned short* tmpg = (unsigned short*)(ws + off); off += 1048576;
  float* decay = (float*)(ws + off);
  unsigned short* og = (unsigned short*)(ws + off);            // alias decay (dead after K5)
  off += 16777216;
  float* aicl = (float*)(ws + off);
  float* obuf = (float*)(ws + off);                            // alias aicl (dead after K4)
  off += 16777216;
  float* gout = (float*)(ws + off); off += 16777216;
  float* rbuf = (float*)(ws + off);
  float* x2   = (float*)(ws + off);                            // alias rbuf (dead after K6)
  off += 16777216;
  float* kbuf = (float*)(ws + off); off += 16777216;
  float* awb  = (float*)(ws + off);
  unsigned short* kf = (unsigned short*)(ws + off);            // alias awb (dead after K5)
  off += 16777216;
  float* bwb  = (float*)(ws + off); off += 16777216;           // total ~187 MB

  dim3 tb(32, 8);
  // weight prep: f32 (K,N) -> bf16 (N,K)
  kt_transpose<<<dim3(32, 32), tb, 0, stream>>>(Wr, WrT, 1024, 1024);
  kt_transpose<<<dim3(32, 32), tb, 0, stream>>>(Wk, WkT, 1024, 1024);
  kt_transpose<<<dim3(32, 32), tb, 0, stream>>>(Wv, WvT, 1024, 1024);
  kt_transpose<<<dim3(32, 32), tb, 0, stream>>>(Wo, WoT, 1024, 1024);
  kt_transpose<<<dim3(128, 32), tb, 0, stream>>>(Wf1, Wf1T, 1024, 4096);
  kt_transpose<<<dim3(32, 128), tb, 0, stream>>>(Wf2, Wf2T, 4096, 1024);
  kt_transpose<<<dim3(2, 32), tb, 0, stream>>>(w1m, w1T, 1024, 64);
  kt_transpose<<<dim3(32, 2), tb, 0, stream>>>(w2m, w2T, 64, 1024);
  kt_transpose<<<dim3(2, 32), tb, 0, stream>>>(a1m, a1T, 1024, 64);
  kt_transpose<<<dim3(32, 2), tb, 0, stream>>>(a2m, a2T, 64, 1024);
  kt_transpose<<<dim3(4, 32), tb, 0, stream>>>(g1m, g1T, 1024, 128);
  kt_transpose<<<dim3(32, 4), tb, 0, stream>>>(g2m, g2T, 128, 1024);

  // K1: pre-LN + attn-LN + shift mixes
  k1_mix<<<Mm, 256, 0, stream>>>(x, lnpw, lnpb, lnaw, lnab, cxr, cxw, cxk, cxv, cxa, cxg,
                                 xln, mixR, mixW, mixK, mixV, mixA, mixG);

  // LoRA chains
  kg_gemm<2><<<dim3(1, 32), 256, 0, stream>>>(mixW, w1T, Mm, 64, 1024, nullptr, tmpw, nullptr, nullptr);
  kg_gemm<6><<<dim3(8, 32), 256, 0, stream>>>(tmpw, w2T, Mm, 1024, 64, decay, nullptr, w0v, nullptr);
  kg_gemm<1><<<dim3(1, 32), 256, 0, stream>>>(mixA, a1T, Mm, 64, 1024, nullptr, tmpa, nullptr, nullptr);
  kg_gemm<5><<<dim3(8, 32), 256, 0, stream>>>(tmpa, a2T, Mm, 1024, 64, aicl, nullptr, a0v, nullptr);
  kg_gemm<3><<<dim3(1, 32), 256, 0, stream>>>(mixG, g1T, Mm, 128, 1024, nullptr, tmpg, nullptr, nullptr);
  kg_gemm<0><<<dim3(8, 32), 256, 0, stream>>>(tmpg, g2T, Mm, 1024, 128, gout, nullptr, nullptr, nullptr);

  // r / k / v projections (v straight into d_out as v_first)
  kg_gemm<0><<<dim3(8, 32), 256, 0, stream>>>(mixR, WrT, Mm, 1024, 1024, rbuf, nullptr, nullptr, nullptr);
  kg_gemm<0><<<dim3(8, 32), 256, 0, stream>>>(mixK, WkT, Mm, 1024, 1024, kbuf, nullptr, nullptr, nullptr);
  kg_gemm<0><<<dim3(8, 32), 256, 0, stream>>>(mixV, WvT, Mm, 1024, 1024, vout, nullptr, nullptr, nullptr);

  // recurrence inputs
  k4_prep<<<Mm, 256, 0, stream>>>(kbuf, aicl, kkv, kav, awb, bwb);
  // WKV7 scan: 256 blocks = (b,h,rowhalf), 1 wave each, chunked LDS staging
  k5_wkv7<<<256, 64, 0, stream>>>(rbuf, decay, kbuf, vout, awb, bwb, obuf);
  // GN + bonus + gate
  k6_out<<<Mm, 256, 0, stream>>>(obuf, rbuf, kbuf, vout, rkv, gnw, gnb, gout, og);
  // o-projection + residual -> x2
  kg_gemm<7><<<dim3(8, 32), 256, 0, stream>>>(og, WoT, Mm, 1024, 1024, x2, nullptr, nullptr, xln);
  // FFN
  k8_ffnmix<<<Mm, 256, 0, stream>>>(x2, lnfw, lnfb, fxk, kf);
  kg_gemm<4><<<dim3(32, 32), 256, 0, stream>>>(kf, Wf1T, Mm, 4096, 1024, nullptr, hbuf, nullptr, nullptr);
  kg_gemm<7><<<dim3(8, 32), 256, 0, stream>>>(hbuf, Wf2T, Mm, 1024, 4096, outx, nullptr, nullptr, x2);
}

// Round 6
// 981.241 us; speedup vs baseline: 1.1717x; 1.1717x over previous
//
#include <hip/hip_runtime.h>

// ---------------- constants ----------------
#define Bb 8
#define Tt 512
#define Cc 1024
#define Hh 16
#define Nh 64
#define Mm 4096            // B*T
#define BTC 4194304        // M*C
#define DEV __device__ __forceinline__

typedef __attribute__((ext_vector_type(8))) short short8;
typedef __attribute__((ext_vector_type(4))) float f32x4;

DEV unsigned short f2bf(float f) {
  unsigned int u = __builtin_bit_cast(unsigned int, f);
  u += 0x7fffu + ((u >> 16) & 1u);
  return (unsigned short)(u >> 16);
}

// ---------------- transpose f32 (K x N) -> bf16 (N x K) ----------------
__global__ __launch_bounds__(256) void kt_transpose(const float* __restrict__ in,
                                                    unsigned short* __restrict__ out,
                                                    int K, int N) {
  __shared__ float tile[32][33];
  int bx = blockIdx.x * 32;  // n
  int by = blockIdx.y * 32;  // k
  int tx = threadIdx.x, ty = threadIdx.y;
  #pragma unroll
  for (int i = ty; i < 32; i += 8) {
    int kk = by + i, nn = bx + tx;
    tile[i][tx] = (kk < K && nn < N) ? in[(size_t)kk * N + nn] : 0.f;
  }
  __syncthreads();
  #pragma unroll
  for (int i = ty; i < 32; i += 8) {
    int nn = bx + i, kk = by + tx;
    if (nn < N && kk < K) out[(size_t)nn * K + kk] = f2bf(tile[tx][i]);
  }
}

// ---------------- block row stats (1024 elems over 256 threads) ----------------
DEV void row_stats(float v0, float v1, float v2, float v3, float* red,
                   float& mu, float& rs, float eps) {
  float s = v0 + v1 + v2 + v3;
  float q = v0 * v0 + v1 * v1 + v2 * v2 + v3 * v3;
  #pragma unroll
  for (int o = 32; o; o >>= 1) { s += __shfl_down(s, o); q += __shfl_down(q, o); }
  int w = threadIdx.x >> 6;
  __syncthreads();
  if ((threadIdx.x & 63) == 0) { red[w] = s; red[4 + w] = q; }
  __syncthreads();
  s = red[0] + red[1] + red[2] + red[3];
  q = red[4] + red[5] + red[6] + red[7];
  mu = s * (1.f / 1024.f);
  float var = q * (1.f / 1024.f) - mu * mu;
  rs = rsqrtf(var + eps);
}

// ---------------- K1: pre-LN + attn-LN + time-shift mixes ----------------
__global__ __launch_bounds__(256) void k1_mix(
    const float* __restrict__ x,
    const float* __restrict__ lnpw, const float* __restrict__ lnpb,
    const float* __restrict__ lnaw, const float* __restrict__ lnab,
    const float* __restrict__ cr, const float* __restrict__ cw,
    const float* __restrict__ ck, const float* __restrict__ cv,
    const float* __restrict__ ca, const float* __restrict__ cg,
    float* __restrict__ xln,
    unsigned short* __restrict__ mR, unsigned short* __restrict__ mW,
    unsigned short* __restrict__ mK, unsigned short* __restrict__ mV,
    unsigned short* __restrict__ mA, unsigned short* __restrict__ mG) {
  __shared__ float red[8];
  const int row = blockIdx.x;
  const int t = row & (Tt - 1);
  const int tid = threadIdx.x;
  const int c = tid * 4;
  const size_t base = (size_t)row * Cc + c;
  float a0 = x[base], a1 = x[base + 1], a2 = x[base + 2], a3 = x[base + 3];
  float mu, rs;
  row_stats(a0, a1, a2, a3, red, mu, rs, 1e-5f);
  float pw0 = lnpw[c], pw1 = lnpw[c + 1], pw2 = lnpw[c + 2], pw3 = lnpw[c + 3];
  float pb0 = lnpb[c], pb1 = lnpb[c + 1], pb2 = lnpb[c + 2], pb3 = lnpb[c + 3];
  float l0 = (a0 - mu) * rs * pw0 + pb0, l1 = (a1 - mu) * rs * pw1 + pb1;
  float l2 = (a2 - mu) * rs * pw2 + pb2, l3 = (a3 - mu) * rs * pw3 + pb3;
  float4 st; st.x = l0; st.y = l1; st.z = l2; st.w = l3;
  *(float4*)(xln + base) = st;
  row_stats(l0, l1, l2, l3, red, mu, rs, 1e-5f);
  float aw0 = lnaw[c], aw1 = lnaw[c + 1], aw2 = lnaw[c + 2], aw3 = lnaw[c + 3];
  float ab0 = lnab[c], ab1 = lnab[c + 1], ab2 = lnab[c + 2], ab3 = lnab[c + 3];
  float n0 = (l0 - mu) * rs * aw0 + ab0, n1 = (l1 - mu) * rs * aw1 + ab1;
  float n2 = (l2 - mu) * rs * aw2 + ab2, n3 = (l3 - mu) * rs * aw3 + ab3;
  float p0 = 0.f, p1 = 0.f, p2 = 0.f, p3 = 0.f;
  if (t > 0) {  // uniform over block
    const size_t pb_ = base - Cc;
    float q0 = x[pb_], q1 = x[pb_ + 1], q2 = x[pb_ + 2], q3 = x[pb_ + 3];
    row_stats(q0, q1, q2, q3, red, mu, rs, 1e-5f);
    float e0 = (q0 - mu) * rs * pw0 + pb0, e1 = (q1 - mu) * rs * pw1 + pb1;
    float e2 = (q2 - mu) * rs * pw2 + pb2, e3 = (q3 - mu) * rs * pw3 + pb3;
    row_stats(e0, e1, e2, e3, red, mu, rs, 1e-5f);
    p0 = (e0 - mu) * rs * aw0 + ab0; p1 = (e1 - mu) * rs * aw1 + ab1;
    p2 = (e2 - mu) * rs * aw2 + ab2; p3 = (e3 - mu) * rs * aw3 + ab3;
  }
  float d0 = p0 - n0, d1 = p1 - n1, d2 = p2 - n2, d3 = p3 - n3;
  #define EMIT(cf, dst) { \
    float f0 = cf[c], f1 = cf[c + 1], f2 = cf[c + 2], f3 = cf[c + 3]; \
    ushort4 u; u.x = f2bf(n0 + d0 * f0); u.y = f2bf(n1 + d1 * f1); \
    u.z = f2bf(n2 + d2 * f2); u.w = f2bf(n3 + d3 * f3); \
    *(ushort4*)(dst + base) = u; }
  EMIT(cr, mR) EMIT(cw, mW) EMIT(ck, mK) EMIT(cv, mV) EMIT(ca, mA) EMIT(cg, mG)
  #undef EMIT
}

// ---------------- generic 128x128x32 bf16 MFMA GEMM ----------------
// A: (M,K) bf16 row-major; Bt: (N,K) bf16 row-major (i.e. B transposed)
// MODE: 0 f32 | 1 bf16 | 2 tanh->bf16 | 3 sigmoid->bf16 | 4 relu^2->bf16
//       5 sigmoid(z+bias[col])->f32 | 6 exp(-sigmoid(z+bias[col])*e^-.5)->f32 | 7 z+res->f32
template <int MODE>
__global__ __launch_bounds__(256) void kg_gemm(
    const unsigned short* __restrict__ A, const unsigned short* __restrict__ Bt,
    int M, int Nn, int K,
    float* __restrict__ outF, unsigned short* __restrict__ outB,
    const float* __restrict__ bias, const float* __restrict__ res) {
  constexpr int PAD = 40;
  __shared__ unsigned short lsA[128 * PAD];
  __shared__ unsigned short lsB[128 * PAD];
  const int tid = threadIdx.x;
  const int lane = tid & 63;
  const int wave = tid >> 6;
  const int wy = wave >> 1, wx = wave & 1;
  const int m0 = blockIdx.y * 128;
  const int n0 = blockIdx.x * 128;
  const int sr = tid >> 2;          // staging row 0..63
  const int sk = (tid & 3) << 3;    // staging k-offset (elems)
  f32x4 acc[4][4];
  #pragma unroll
  for (int i = 0; i < 4; ++i)
    #pragma unroll
    for (int j = 0; j < 4; ++j) { f32x4 z = {0.f, 0.f, 0.f, 0.f}; acc[i][j] = z; }
  const int fr = lane & 15;
  const int fk = (lane >> 4) << 3;
  for (int k0 = 0; k0 < K; k0 += 32) {
    uint4 av0 = *(const uint4*)(A + (size_t)(m0 + sr) * K + k0 + sk);
    uint4 av1 = *(const uint4*)(A + (size_t)(m0 + sr + 64) * K + k0 + sk);
    uint4 bv0 = {0u, 0u, 0u, 0u}, bv1 = {0u, 0u, 0u, 0u};
    if (n0 + sr < Nn)      bv0 = *(const uint4*)(Bt + (size_t)(n0 + sr) * K + k0 + sk);
    if (n0 + sr + 64 < Nn) bv1 = *(const uint4*)(Bt + (size_t)(n0 + sr + 64) * K + k0 + sk);
    __syncthreads();
    *(uint4*)(lsA + sr * PAD + sk) = av0;
    *(uint4*)(lsA + (sr + 64) * PAD + sk) = av1;
    *(uint4*)(lsB + sr * PAD + sk) = bv0;
    *(uint4*)(lsB + (sr + 64) * PAD + sk) = bv1;
    __syncthreads();
    short8 af[4], bf[4];
    #pragma unroll
    for (int mt = 0; mt < 4; ++mt)
      af[mt] = *(const short8*)(lsA + (wy * 64 + mt * 16 + fr) * PAD + fk);
    #pragma unroll
    for (int nt = 0; nt < 4; ++nt)
      bf[nt] = *(const short8*)(lsB + (wx * 64 + nt * 16 + fr) * PAD + fk);
    #pragma unroll
    for (int mt = 0; mt < 4; ++mt)
      #pragma unroll
      for (int nt = 0; nt < 4; ++nt)
        acc[mt][nt] = __builtin_amdgcn_mfma_f32_16x16x32_bf16(af[mt], bf[nt], acc[mt][nt], 0, 0, 0);
  }
  const int rbase = (lane >> 4) << 2;
  const int cbase = lane & 15;
  #pragma unroll
  for (int mt = 0; mt < 4; ++mt)
    #pragma unroll
    for (int nt = 0; nt < 4; ++nt)
      #pragma unroll
      for (int rr = 0; rr < 4; ++rr) {
        int row = m0 + wy * 64 + mt * 16 + rbase + rr;
        int col = n0 + wx * 64 + nt * 16 + cbase;
        if (col < Nn) {
          size_t oi = (size_t)row * Nn + col;
          float z = acc[mt][nt][rr];
          if constexpr (MODE == 0) outF[oi] = z;
          else if constexpr (MODE == 1) outB[oi] = f2bf(z);
          else if constexpr (MODE == 2) outB[oi] = f2bf(tanhf(z));
          else if constexpr (MODE == 3) outB[oi] = f2bf(1.f / (1.f + expf(-z)));
          else if constexpr (MODE == 4) { float m = fmaxf(z, 0.f); outB[oi] = f2bf(m * m); }
          else if constexpr (MODE == 5) { z += bias[col]; outF[oi] = 1.f / (1.f + expf(-z)); }
          else if constexpr (MODE == 6) {
            z += bias[col];
            float sg = 1.f / (1.f + expf(-z));
            outF[oi] = expf(-0.6065306597126334f * sg);
          } else { outF[oi] = z + res[oi]; }
        }
      }
}

// ---------------- K4: kk-normalize, a/b vectors, k update (in place) ----------------
__global__ __launch_bounds__(256) void k4_prep(
    float* __restrict__ k, const float* __restrict__ a,
    const float* __restrict__ kkc, const float* __restrict__ kac,
    float* __restrict__ aw, float* __restrict__ bw) {
  const int row = blockIdx.x, tid = threadIdx.x;
  const int c = tid * 4;
  const size_t base = (size_t)row * Cc + c;
  float k0 = k[base], k1 = k[base + 1], k2 = k[base + 2], k3 = k[base + 3];
  float a0 = a[base], a1 = a[base + 1], a2 = a[base + 2], a3 = a[base + 3];
  float h0 = k0 * kkc[c], h1 = k1 * kkc[c + 1], h2 = k2 * kkc[c + 2], h3 = k3 * kkc[c + 3];
  float ss = h0 * h0 + h1 * h1 + h2 * h2 + h3 * h3;
  #pragma unroll
  for (int m = 8; m; m >>= 1) ss += __shfl_xor(ss, m);
  float inv = 1.f / fmaxf(sqrtf(ss), 1e-12f);
  h0 *= inv; h1 *= inv; h2 *= inv; h3 *= inv;
  float4 v4;
  v4.x = -h0; v4.y = -h1; v4.z = -h2; v4.w = -h3;
  *(float4*)(aw + base) = v4;
  v4.x = h0 * a0; v4.y = h1 * a1; v4.z = h2 * a2; v4.w = h3 * a3;
  *(float4*)(bw + base) = v4;
  v4.x = k0 * (1.f + (a0 - 1.f) * kac[c]);
  v4.y = k1 * (1.f + (a1 - 1.f) * kac[c + 1]);
  v4.z = k2 * (1.f + (a2 - 1.f) * kac[c + 2]);
  v4.w = k3 * (1.f + (a3 - 1.f) * kac[c + 3]);
  *(float4*)(k + base) = v4;
}

// ---------------- K5: WKV7 recurrence — chunked staging, 4 blocks/(b,h) ----------------
// 512 blocks = (rq, bh): rq = row-quarter (16 rows), bh = (b,h). Same-bh blocks
// are 128 apart -> same XCD under %8 dispatch (128%8==0) -> L2-shared staging.
// Lane = (row within 16) + 16*cq, cq = column quarter (16 cols). S = 16 VGPRs.
// Chunked prefetch (CS=8): 12 uint4 regs (48 VGPRs — NO spill; R5's R[24]=96
// spilled to scratch, the 48 MB WRITE_SIZE pathology), committed to LDS
// double-buffer at chunk start, loads for chunk c+1 issued immediately after
// (one full chunk of slack, straight-line). Per step: 21 ds_read_b128 (half of
// R5's 41 — the LDS issue floor), sa/out reduced via shfl_xor(16)+shfl_xor(32).
#define CS 8
__global__ __launch_bounds__(64) void k5_wkv7(
    const float* __restrict__ r, const float* __restrict__ dec,
    const float* __restrict__ k, const float* __restrict__ v,
    const float* __restrict__ aw, const float* __restrict__ bw,
    float* __restrict__ o) {
  const int blk = blockIdx.x;          // 0..511
  const int bh = blk & 127, rq = blk >> 7;
  const int b = bh >> 4, h = bh & 15;
  const int lane = threadIdx.x;
  const int r16 = lane & 15;           // row within quarter
  const int cq = lane >> 4;            // column quarter (0..3)
  const int row = rq * 16 + r16;       // state row i
  const int cb = cq << 4;              // column base j0

  // chunk layout: [6][CS][64] floats; arrs: a,d,b,k,r,v
  __shared__ float buf[2][6 * CS * 64];

  float S[16];
  #pragma unroll
  for (int j = 0; j < 16; ++j) S[j] = 0.f;

  const size_t base = (size_t)b * Tt * Cc + (size_t)h * Nh;
  // staging: one uint4 per (arr,sg): lanes cover 4 steps x 64 floats.
  // global: (cstart + sg*4 + (lane>>4))*Cc + (lane&15)*4
  // LDS:    arr*(CS*64) + (sg*4 + lane>>4)*64 + (lane&15)*4 = arr*512 + sg*256 + lane*4
  const int loff = ((lane >> 4) << 10) + ((lane & 15) << 2);
  const int soff = lane << 2;

  uint4 R[12];
  #define LOADC(cstart) { \
    const size_t g0 = base + (size_t)(cstart) * Cc + loff; \
    _Pragma("unroll") \
    for (int sg = 0; sg < 2; ++sg) { \
      R[0 * 2 + sg] = *(const uint4*)(aw  + g0 + sg * 4096); \
      R[1 * 2 + sg] = *(const uint4*)(dec + g0 + sg * 4096); \
      R[2 * 2 + sg] = *(const uint4*)(bw  + g0 + sg * 4096); \
      R[3 * 2 + sg] = *(const uint4*)(k   + g0 + sg * 4096); \
      R[4 * 2 + sg] = *(const uint4*)(r   + g0 + sg * 4096); \
      R[5 * 2 + sg] = *(const uint4*)(v   + g0 + sg * 4096); \
    } }

  LOADC(0)

  #pragma unroll 1
  for (int c = 0; c < Tt / CS; ++c) {
    float* bp = buf[c & 1];
    // commit chunk c (regs loaded one full chunk ago -> huge vmcnt slack)
    #pragma unroll
    for (int arr = 0; arr < 6; ++arr)
      #pragma unroll
      for (int sg = 0; sg < 2; ++sg)
        *(uint4*)(bp + arr * (CS * 64) + sg * 256 + soff) = R[arr * 2 + sg];
    // issue chunk c+1 loads (clamped, branchless)
    const int cn = (c + 1 < Tt / CS) ? (c + 1) : c;
    LOADC(cn * CS)
    // compute CS steps from LDS only
    #pragma unroll 1
    for (int s = 0; s < CS; ++s) {
      const int t = c * CS + s;
      const float* sp = bp + s * 64;
      const float* ap  = sp + cb;
      const float* dp  = sp + 1 * (CS * 64) + cb;
      const float* bpp = sp + 2 * (CS * 64) + cb;
      const float* kp  = sp + 3 * (CS * 64) + cb;
      const float* rp  = sp + 4 * (CS * 64) + cb;
      const float  vv  = sp[5 * (CS * 64) + row];

      float sa0 = 0.f, sa1 = 0.f, sa2 = 0.f, sa3 = 0.f;
      #pragma unroll
      for (int jj = 0; jj < 16; jj += 4) {
        float4 a4 = *(const float4*)(ap + jj);
        sa0 = fmaf(S[jj + 0], a4.x, sa0);
        sa1 = fmaf(S[jj + 1], a4.y, sa1);
        sa2 = fmaf(S[jj + 2], a4.z, sa2);
        sa3 = fmaf(S[jj + 3], a4.w, sa3);
      }
      float sa = (sa0 + sa1) + (sa2 + sa3);
      sa += __shfl_xor(sa, 16);
      sa += __shfl_xor(sa, 32);

      float o0 = 0.f, o1 = 0.f, o2 = 0.f, o3 = 0.f;
      #pragma unroll
      for (int jj = 0; jj < 16; jj += 4) {
        float4 d4 = *(const float4*)(dp + jj);
        float4 b4 = *(const float4*)(bpp + jj);
        float4 k4 = *(const float4*)(kp + jj);
        float4 r4 = *(const float4*)(rp + jj);
        S[jj + 0] = fmaf(S[jj + 0], d4.x, fmaf(vv, k4.x, sa * b4.x));
        o0 = fmaf(S[jj + 0], r4.x, o0);
        S[jj + 1] = fmaf(S[jj + 1], d4.y, fmaf(vv, k4.y, sa * b4.y));
        o1 = fmaf(S[jj + 1], r4.y, o1);
        S[jj + 2] = fmaf(S[jj + 2], d4.z, fmaf(vv, k4.z, sa * b4.z));
        o2 = fmaf(S[jj + 2], r4.z, o2);
        S[jj + 3] = fmaf(S[jj + 3], d4.w, fmaf(vv, k4.w, sa * b4.w));
        o3 = fmaf(S[jj + 3], r4.w, o3);
      }
      float oo = (o0 + o1) + (o2 + o3);
      oo += __shfl_xor(oo, 16);
      oo += __shfl_xor(oo, 32);
      if (cq == 0) o[base + (size_t)t * Cc + row] = oo;
    }
  }
  #undef LOADC
}

// ---------------- K6: head GroupNorm + rk bonus + gate ----------------
__global__ __launch_bounds__(256) void k6_out(
    const float* __restrict__ o, const float* __restrict__ r, const float* __restrict__ k,
    const float* __restrict__ v, const float* __restrict__ rk,
    const float* __restrict__ gnw, const float* __restrict__ gnb,
    const float* __restrict__ g, unsigned short* __restrict__ og) {
  const int row = blockIdx.x, tid = threadIdx.x;
  const int c = tid * 4;
  const size_t base = (size_t)row * Cc + c;
  float o0 = o[base], o1 = o[base + 1], o2 = o[base + 2], o3 = o[base + 3];
  float r0 = r[base], r1 = r[base + 1], r2 = r[base + 2], r3 = r[base + 3];
  float k0 = k[base], k1 = k[base + 1], k2 = k[base + 2], k3 = k[base + 3];
  float s = o0 + o1 + o2 + o3;
  float q = o0 * o0 + o1 * o1 + o2 * o2 + o3 * o3;
  float bs = r0 * k0 * rk[c] + r1 * k1 * rk[c + 1] + r2 * k2 * rk[c + 2] + r3 * k3 * rk[c + 3];
  #pragma unroll
  for (int m = 8; m; m >>= 1) {
    s += __shfl_xor(s, m); q += __shfl_xor(q, m); bs += __shfl_xor(bs, m);
  }
  float mu = s * (1.f / 64.f);
  float var = q * (1.f / 64.f) - mu * mu;
  float rs = rsqrtf(var + 64e-5f);
  float v0 = v[base], v1 = v[base + 1], v2 = v[base + 2], v3 = v[base + 3];
  float z0 = (o0 - mu) * rs * gnw[c] + gnb[c] + bs * v0;
  float z1 = (o1 - mu) * rs * gnw[c + 1] + gnb[c + 1] + bs * v1;
  float z2 = (o2 - mu) * rs * gnw[c + 2] + gnb[c + 2] + bs * v2;
  float z3 = (o3 - mu) * rs * gnw[c + 3] + gnb[c + 3] + bs * v3;
  ushort4 u;
  u.x = f2bf(z0 * g[base]); u.y = f2bf(z1 * g[base + 1]);
  u.z = f2bf(z2 * g[base + 2]); u.w = f2bf(z3 * g[base + 3]);
  *(ushort4*)(og + base) = u;
}

// ---------------- K8: FFN LN + time-shift mix ----------------
__global__ __launch_bounds__(256) void k8_ffnmix(
    const float* __restrict__ x2, const float* __restrict__ lnw, const float* __restrict__ lnb,
    const float* __restrict__ fxk, unsigned short* __restrict__ kf) {
  __shared__ float red[8];
  const int row = blockIdx.x;
  const int t = row & (Tt - 1);
  const int tid = threadIdx.x;
  const int c = tid * 4;
  const size_t base = (size_t)row * Cc + c;
  float a0 = x2[base], a1 = x2[base + 1], a2 = x2[base + 2], a3 = x2[base + 3];
  float mu, rs;
  row_stats(a0, a1, a2, a3, red, mu, rs, 1e-5f);
  float w0 = lnw[c], w1 = lnw[c + 1], w2 = lnw[c + 2], w3 = lnw[c + 3];
  float b0 = lnb[c], b1 = lnb[c + 1], b2 = lnb[c + 2], b3 = lnb[c + 3];
  float f0 = (a0 - mu) * rs * w0 + b0, f1 = (a1 - mu) * rs * w1 + b1;
  float f2 = (a2 - mu) * rs * w2 + b2, f3 = (a3 - mu) * rs * w3 + b3;
  float p0 = 0.f, p1 = 0.f, p2 = 0.f, p3 = 0.f;
  if (t > 0) {
    const size_t pb_ = base - Cc;
    float q0 = x2[pb_], q1 = x2[pb_ + 1], q2 = x2[pb_ + 2], q3 = x2[pb_ + 3];
    row_stats(q0, q1, q2, q3, red, mu, rs, 1e-5f);
    p0 = (q0 - mu) * rs * w0 + b0; p1 = (q1 - mu) * rs * w1 + b1;
    p2 = (q2 - mu) * rs * w2 + b2; p3 = (q3 - mu) * rs * w3 + b3;
  }
  ushort4 u;
  u.x = f2bf(f0 + (p0 - f0) * fxk[c]);
  u.y = f2bf(f1 + (p1 - f1) * fxk[c + 1]);
  u.z = f2bf(f2 + (p2 - f2) * fxk[c + 2]);
  u.w = f2bf(f3 + (p3 - f3) * fxk[c + 3]);
  *(ushort4*)(kf + base) = u;
}

// ---------------- host ----------------
extern "C" void kernel_launch(void* const* d_in, const int* in_sizes, int n_in,
                              void* d_out, int out_size, void* d_ws, size_t ws_size,
                              hipStream_t stream) {
  (void)in_sizes; (void)n_in; (void)out_size; (void)ws_size;
  const float* x    = (const float*)d_in[0];
  const float* lnpw = (const float*)d_in[2];
  const float* lnpb = (const float*)d_in[3];
  const float* lnaw = (const float*)d_in[4];
  const float* lnab = (const float*)d_in[5];
  const float* lnfw = (const float*)d_in[6];
  const float* lnfb = (const float*)d_in[7];
  const float* cxr  = (const float*)d_in[8];
  const float* cxw  = (const float*)d_in[9];
  const float* cxk  = (const float*)d_in[10];
  const float* cxv  = (const float*)d_in[11];
  const float* cxa  = (const float*)d_in[12];
  const float* cxg  = (const float*)d_in[13];
  const float* w0v  = (const float*)d_in[14];
  const float* w1m  = (const float*)d_in[15];
  const float* w2m  = (const float*)d_in[16];
  const float* a0v  = (const float*)d_in[17];
  const float* a1m  = (const float*)d_in[18];
  const float* a2m  = (const float*)d_in[19];
  const float* g1m  = (const float*)d_in[20];
  const float* g2m  = (const float*)d_in[21];
  const float* kkv  = (const float*)d_in[22];
  const float* kav  = (const float*)d_in[23];
  const float* rkv  = (const float*)d_in[24];
  const float* Wr   = (const float*)d_in[25];
  const float* Wk   = (const float*)d_in[26];
  const float* Wv   = (const float*)d_in[27];
  const float* Wo   = (const float*)d_in[28];
  const float* gnw  = (const float*)d_in[29];
  const float* gnb  = (const float*)d_in[30];
  const float* fxk  = (const float*)d_in[31];
  const float* Wf1  = (const float*)d_in[32];
  const float* Wf2  = (const float*)d_in[33];

  char* ws = (char*)d_ws;
  float* outx = (float*)d_out;          // final x (B,T,C)
  float* vout = outx + BTC;             // v_first = v (B,T,C)

  // workspace layout (all offsets multiples of big pow2; aliases noted)
  size_t off = 0;
  unsigned short* WrT  = (unsigned short*)(ws + off); off += 2097152;
  unsigned short* WkT  = (unsigned short*)(ws + off); off += 2097152;
  unsigned short* WvT  = (unsigned short*)(ws + off); off += 2097152;
  unsigned short* WoT  = (unsigned short*)(ws + off); off += 2097152;
  unsigned short* Wf1T = (unsigned short*)(ws + off); off += 8388608;
  unsigned short* Wf2T = (unsigned short*)(ws + off); off += 8388608;
  unsigned short* w1T  = (unsigned short*)(ws + off); off += 131072;
  unsigned short* w2T  = (unsigned short*)(ws + off); off += 131072;
  unsigned short* a1T  = (unsigned short*)(ws + off); off += 131072;
  unsigned short* a2T  = (unsigned short*)(ws + off); off += 131072;
  unsigned short* g1T  = (unsigned short*)(ws + off); off += 262144;
  unsigned short* g2T  = (unsigned short*)(ws + off); off += 262144;
  float* xln = (float*)(ws + off); off += 16777216;
  unsigned short* mixR = (unsigned short*)(ws + off);          // 6 x 8388608
  unsigned short* mixW = (unsigned short*)(ws + off + 8388608);
  unsigned short* mixK = (unsigned short*)(ws + off + 16777216);
  unsigned short* mixV = (unsigned short*)(ws + off + 25165824);
  unsigned short* mixA = (unsigned short*)(ws + off + 33554432);
  unsigned short* mixG = (unsigned short*)(ws + off + 41943040);
  unsigned short* hbuf = (unsigned short*)(ws + off);          // alias mix (dead by then)
  off += 50331648;
  unsigned short* tmpw = (unsigned short*)(ws + off); off += 524288;
  unsigned short* tmpa = (unsigned short*)(ws + off); off += 524288;
  unsigned short* tmpg = (unsigned short*)(ws + off); off += 1048576;
  float* decay = (float*)(ws + off);
  unsigned short* og = (unsigned short*)(ws + off);            // alias decay (dead after K5)
  off += 16777216;
  float* aicl = (float*)(ws + off);
  float* obuf = (float*)(ws + off);                            // alias aicl (dead after K4)
  off += 16777216;
  float* gout = (float*)(ws + off); off += 16777216;
  float* rbuf = (float*)(ws + off);
  float* x2   = (float*)(ws + off);                            // alias rbuf (dead after K6)
  off += 16777216;
  float* kbuf = (float*)(ws + off); off += 16777216;
  float* awb  = (float*)(ws + off);
  unsigned short* kf = (unsigned short*)(ws + off);            // alias awb (dead after K5)
  off += 16777216;
  float* bwb  = (float*)(ws + off); off += 16777216;           // total ~187 MB

  dim3 tb(32, 8);
  // weight prep: f32 (K,N) -> bf16 (N,K)
  kt_transpose<<<dim3(32, 32), tb, 0, stream>>>(Wr, WrT, 1024, 1024);
  kt_transpose<<<dim3(32, 32), tb, 0, stream>>>(Wk, WkT, 1024, 1024);
  kt_transpose<<<dim3(32, 32), tb, 0, stream>>>(Wv, WvT, 1024, 1024);
  kt_transpose<<<dim3(32, 32), tb, 0, stream>>>(Wo, WoT, 1024, 1024);
  kt_transpose<<<dim3(128, 32), tb, 0, stream>>>(Wf1, Wf1T, 1024, 4096);
  kt_transpose<<<dim3(32, 128), tb, 0, stream>>>(Wf2, Wf2T, 4096, 1024);
  kt_transpose<<<dim3(2, 32), tb, 0, stream>>>(w1m, w1T, 1024, 64);
  kt_transpose<<<dim3(32, 2), tb, 0, stream>>>(w2m, w2T, 64, 1024);
  kt_transpose<<<dim3(2, 32), tb, 0, stream>>>(a1m, a1T, 1024, 64);
  kt_transpose<<<dim3(32, 2), tb, 0, stream>>>(a2m, a2T, 64, 1024);
  kt_transpose<<<dim3(4, 32), tb, 0, stream>>>(g1m, g1T, 1024, 128);
  kt_transpose<<<dim3(32, 4), tb, 0, stream>>>(g2m, g2T, 128, 1024);

  // K1: pre-LN + attn-LN + shift mixes
  k1_mix<<<Mm, 256, 0, stream>>>(x, lnpw, lnpb, lnaw, lnab, cxr, cxw, cxk, cxv, cxa, cxg,
                                 xln, mixR, mixW, mixK, mixV, mixA, mixG);

  // LoRA chains
  kg_gemm<2><<<dim3(1, 32), 256, 0, stream>>>(mixW, w1T, Mm, 64, 1024, nullptr, tmpw, nullptr, nullptr);
  kg_gemm<6><<<dim3(8, 32), 256, 0, stream>>>(tmpw, w2T, Mm, 1024, 64, decay, nullptr, w0v, nullptr);
  kg_gemm<1><<<dim3(1, 32), 256, 0, stream>>>(mixA, a1T, Mm, 64, 1024, nullptr, tmpa, nullptr, nullptr);
  kg_gemm<5><<<dim3(8, 32), 256, 0, stream>>>(tmpa, a2T, Mm, 1024, 64, aicl, nullptr, a0v, nullptr);
  kg_gemm<3><<<dim3(1, 32), 256, 0, stream>>>(mixG, g1T, Mm, 128, 1024, nullptr, tmpg, nullptr, nullptr);
  kg_gemm<0><<<dim3(8, 32), 256, 0, stream>>>(tmpg, g2T, Mm, 1024, 128, gout, nullptr, nullptr, nullptr);

  // r / k / v projections (v straight into d_out as v_first)
  kg_gemm<0><<<dim3(8, 32), 256, 0, stream>>>(mixR, WrT, Mm, 1024, 1024, rbuf, nullptr, nullptr, nullptr);
  kg_gemm<0><<<dim3(8, 32), 256, 0, stream>>>(mixK, WkT, Mm, 1024, 1024, kbuf, nullptr, nullptr, nullptr);
  kg_gemm<0><<<dim3(8, 32), 256, 0, stream>>>(mixV, WvT, Mm, 1024, 1024, vout, nullptr, nullptr, nullptr);

  // recurrence inputs
  k4_prep<<<Mm, 256, 0, stream>>>(kbuf, aicl, kkv, kav, awb, bwb);
  // WKV7 scan: 512 blocks = (rq, bh), 1 wave each, chunked LDS staging
  k5_wkv7<<<512, 64, 0, stream>>>(rbuf, decay, kbuf, vout, awb, bwb, obuf);
  // GN + bonus + gate
  k6_out<<<Mm, 256, 0, stream>>>(obuf, rbuf, kbuf, vout, rkv, gnw, gnb, gout, og);
  // o-projection + residual -> x2
  kg_gemm<7><<<dim3(8, 32), 256, 0, stream>>>(og, WoT, Mm, 1024, 1024, x2, nullptr, nullptr, xln);
  // FFN
  k8_ffnmix<<<Mm, 256, 0, stream>>>(x2, lnfw, lnfb, fxk, kf);
  kg_gemm<4><<<dim3(32, 32), 256, 0, stream>>>(kf, Wf1T, Mm, 4096, 1024, nullptr, hbuf, nullptr, nullptr);
  kg_gemm<7><<<dim3(8, 32), 256, 0, stream>>>(hbuf, Wf2T, Mm, 1024, 4096, outx, nullptr, nullptr, x2);
}

// Round 7
// 936.893 us; speedup vs baseline: 1.2271x; 1.0473x over previous
//
#include <hip/hip_runtime.h>

// ---------------- constants ----------------
#define Bb 8
#define Tt 512
#define Cc 1024
#define Hh 16
#define Nh 64
#define Mm 4096            // B*T
#define BTC 4194304        // M*C
#define DEV __device__ __forceinline__

typedef __attribute__((ext_vector_type(8))) short short8;
typedef __attribute__((ext_vector_type(4))) float f32x4;

DEV unsigned short f2bf(float f) {
  unsigned int u = __builtin_bit_cast(unsigned int, f);
  u += 0x7fffu + ((u >> 16) & 1u);
  return (unsigned short)(u >> 16);
}

// quad_perm butterfly add via DPP — pure VALU, no LDS/lgkm latency.
// 0xB1 = [1,0,3,2] (xor1), 0x4E = [2,3,0,1] (xor2)
template <int CTRL>
DEV float dppadd(float x) {
  int xi = __builtin_bit_cast(int, x);
  int yi = __builtin_amdgcn_update_dpp(0, xi, CTRL, 0xF, 0xF, true);
  return x + __builtin_bit_cast(float, yi);
}

// ---------------- transpose f32 (K x N) -> bf16 (N x K) ----------------
__global__ __launch_bounds__(256) void kt_transpose(const float* __restrict__ in,
                                                    unsigned short* __restrict__ out,
                                                    int K, int N) {
  __shared__ float tile[32][33];
  int bx = blockIdx.x * 32;  // n
  int by = blockIdx.y * 32;  // k
  int tx = threadIdx.x, ty = threadIdx.y;
  #pragma unroll
  for (int i = ty; i < 32; i += 8) {
    int kk = by + i, nn = bx + tx;
    tile[i][tx] = (kk < K && nn < N) ? in[(size_t)kk * N + nn] : 0.f;
  }
  __syncthreads();
  #pragma unroll
  for (int i = ty; i < 32; i += 8) {
    int nn = bx + i, kk = by + tx;
    if (nn < N && kk < K) out[(size_t)nn * K + kk] = f2bf(tile[tx][i]);
  }
}

// ---------------- block row stats (1024 elems over 256 threads) ----------------
DEV void row_stats(float v0, float v1, float v2, float v3, float* red,
                   float& mu, float& rs, float eps) {
  float s = v0 + v1 + v2 + v3;
  float q = v0 * v0 + v1 * v1 + v2 * v2 + v3 * v3;
  #pragma unroll
  for (int o = 32; o; o >>= 1) { s += __shfl_down(s, o); q += __shfl_down(q, o); }
  int w = threadIdx.x >> 6;
  __syncthreads();
  if ((threadIdx.x & 63) == 0) { red[w] = s; red[4 + w] = q; }
  __syncthreads();
  s = red[0] + red[1] + red[2] + red[3];
  q = red[4] + red[5] + red[6] + red[7];
  mu = s * (1.f / 1024.f);
  float var = q * (1.f / 1024.f) - mu * mu;
  rs = rsqrtf(var + eps);
}

// ---------------- K1: pre-LN + attn-LN + time-shift mixes ----------------
__global__ __launch_bounds__(256) void k1_mix(
    const float* __restrict__ x,
    const float* __restrict__ lnpw, const float* __restrict__ lnpb,
    const float* __restrict__ lnaw, const float* __restrict__ lnab,
    const float* __restrict__ cr, const float* __restrict__ cw,
    const float* __restrict__ ck, const float* __restrict__ cv,
    const float* __restrict__ ca, const float* __restrict__ cg,
    float* __restrict__ xln,
    unsigned short* __restrict__ mR, unsigned short* __restrict__ mW,
    unsigned short* __restrict__ mK, unsigned short* __restrict__ mV,
    unsigned short* __restrict__ mA, unsigned short* __restrict__ mG) {
  __shared__ float red[8];
  const int row = blockIdx.x;
  const int t = row & (Tt - 1);
  const int tid = threadIdx.x;
  const int c = tid * 4;
  const size_t base = (size_t)row * Cc + c;
  float a0 = x[base], a1 = x[base + 1], a2 = x[base + 2], a3 = x[base + 3];
  float mu, rs;
  row_stats(a0, a1, a2, a3, red, mu, rs, 1e-5f);
  float pw0 = lnpw[c], pw1 = lnpw[c + 1], pw2 = lnpw[c + 2], pw3 = lnpw[c + 3];
  float pb0 = lnpb[c], pb1 = lnpb[c + 1], pb2 = lnpb[c + 2], pb3 = lnpb[c + 3];
  float l0 = (a0 - mu) * rs * pw0 + pb0, l1 = (a1 - mu) * rs * pw1 + pb1;
  float l2 = (a2 - mu) * rs * pw2 + pb2, l3 = (a3 - mu) * rs * pw3 + pb3;
  float4 st; st.x = l0; st.y = l1; st.z = l2; st.w = l3;
  *(float4*)(xln + base) = st;
  row_stats(l0, l1, l2, l3, red, mu, rs, 1e-5f);
  float aw0 = lnaw[c], aw1 = lnaw[c + 1], aw2 = lnaw[c + 2], aw3 = lnaw[c + 3];
  float ab0 = lnab[c], ab1 = lnab[c + 1], ab2 = lnab[c + 2], ab3 = lnab[c + 3];
  float n0 = (l0 - mu) * rs * aw0 + ab0, n1 = (l1 - mu) * rs * aw1 + ab1;
  float n2 = (l2 - mu) * rs * aw2 + ab2, n3 = (l3 - mu) * rs * aw3 + ab3;
  float p0 = 0.f, p1 = 0.f, p2 = 0.f, p3 = 0.f;
  if (t > 0) {  // uniform over block
    const size_t pb_ = base - Cc;
    float q0 = x[pb_], q1 = x[pb_ + 1], q2 = x[pb_ + 2], q3 = x[pb_ + 3];
    row_stats(q0, q1, q2, q3, red, mu, rs, 1e-5f);
    float e0 = (q0 - mu) * rs * pw0 + pb0, e1 = (q1 - mu) * rs * pw1 + pb1;
    float e2 = (q2 - mu) * rs * pw2 + pb2, e3 = (q3 - mu) * rs * pw3 + pb3;
    row_stats(e0, e1, e2, e3, red, mu, rs, 1e-5f);
    p0 = (e0 - mu) * rs * aw0 + ab0; p1 = (e1 - mu) * rs * aw1 + ab1;
    p2 = (e2 - mu) * rs * aw2 + ab2; p3 = (e3 - mu) * rs * aw3 + ab3;
  }
  float d0 = p0 - n0, d1 = p1 - n1, d2 = p2 - n2, d3 = p3 - n3;
  #define EMIT(cf, dst) { \
    float f0 = cf[c], f1 = cf[c + 1], f2 = cf[c + 2], f3 = cf[c + 3]; \
    ushort4 u; u.x = f2bf(n0 + d0 * f0); u.y = f2bf(n1 + d1 * f1); \
    u.z = f2bf(n2 + d2 * f2); u.w = f2bf(n3 + d3 * f3); \
    *(ushort4*)(dst + base) = u; }
  EMIT(cr, mR) EMIT(cw, mW) EMIT(ck, mK) EMIT(cv, mV) EMIT(ca, mA) EMIT(cg, mG)
  #undef EMIT
}

// ---------------- generic 128x128x32 bf16 MFMA GEMM (m97-style) ----------------
// A: (M,K) bf16 row-major; Bt: (N,K) bf16 row-major. Staging via
// global_load_lds width=16 (no VGPR round-trip, no staging regs — m93->m97
// was 517->874 TF from exactly this). Unpadded 128x32 tiles (lane-order LDS
// contiguity required by LDS-DMA). OOB B-rows clamped (dup rows never stored).
// MODE: 0 f32 | 1 bf16 | 2 tanh->bf16 | 3 sigmoid->bf16 | 4 relu^2->bf16
//       5 sigmoid(z+bias[col])->f32 | 6 exp(-sigmoid(z+bias[col])*e^-.5)->f32 | 7 z+res->f32
DEV void gll16(const unsigned short* g, unsigned short* l) {
  __builtin_amdgcn_global_load_lds(
      (const __attribute__((address_space(1))) void*)g,
      (__attribute__((address_space(3))) void*)l, 16, 0, 0);
}

template <int MODE>
__global__ __launch_bounds__(256) void kg_gemm(
    const unsigned short* __restrict__ A, const unsigned short* __restrict__ Bt,
    int M, int Nn, int K,
    float* __restrict__ outF, unsigned short* __restrict__ outB,
    const float* __restrict__ bias, const float* __restrict__ res) {
  __shared__ unsigned short lsA[128 * 32];
  __shared__ unsigned short lsB[128 * 32];
  const int tid = threadIdx.x;
  const int lane = tid & 63;
  const int wave = tid >> 6;
  const int wy = wave >> 1, wx = wave & 1;
  const int m0 = blockIdx.y * 128;
  const int n0 = blockIdx.x * 128;
  const int sl4 = lane >> 2;        // row within 16-row block
  const int sc = (lane & 3) << 3;   // k-elem offset {0,8,16,24}
  f32x4 acc[4][4];
  #pragma unroll
  for (int i = 0; i < 4; ++i)
    #pragma unroll
    for (int j = 0; j < 4; ++j) { f32x4 z = {0.f, 0.f, 0.f, 0.f}; acc[i][j] = z; }
  const int fr = lane & 15;
  const int fk = (lane >> 4) << 3;
  for (int k0 = 0; k0 < K; k0 += 32) {
    // stage: per wave 2 A-blocks + 2 B-blocks of 16 rows x 32 k (1 KB each)
    #pragma unroll
    for (int j = 0; j < 2; ++j) {
      const int rb = (wave + j * 4) * 16;          // 0..112
      const int ar = m0 + rb + sl4;
      gll16(A + (size_t)ar * K + k0 + sc, lsA + rb * 32);
      int br = n0 + rb + sl4;
      br = br < Nn ? br : Nn - 1;                  // clamp (dup rows unstored)
      gll16(Bt + (size_t)br * K + k0 + sc, lsB + rb * 32);
    }
    __syncthreads();   // compiler inserts vmcnt(0) drain before barrier
    short8 af[4], bf[4];
    #pragma unroll
    for (int mt = 0; mt < 4; ++mt)
      af[mt] = *(const short8*)(lsA + (wy * 64 + mt * 16 + fr) * 32 + fk);
    #pragma unroll
    for (int nt = 0; nt < 4; ++nt)
      bf[nt] = *(const short8*)(lsB + (wx * 64 + nt * 16 + fr) * 32 + fk);
    #pragma unroll
    for (int mt = 0; mt < 4; ++mt)
      #pragma unroll
      for (int nt = 0; nt < 4; ++nt)
        acc[mt][nt] = __builtin_amdgcn_mfma_f32_16x16x32_bf16(af[mt], bf[nt], acc[mt][nt], 0, 0, 0);
    __syncthreads();
  }
  const int rbase = (lane >> 4) << 2;
  const int cbase = lane & 15;
  #pragma unroll
  for (int mt = 0; mt < 4; ++mt)
    #pragma unroll
    for (int nt = 0; nt < 4; ++nt)
      #pragma unroll
      for (int rr = 0; rr < 4; ++rr) {
        int row = m0 + wy * 64 + mt * 16 + rbase + rr;
        int col = n0 + wx * 64 + nt * 16 + cbase;
        if (col < Nn) {
          size_t oi = (size_t)row * Nn + col;
          float z = acc[mt][nt][rr];
          if constexpr (MODE == 0) outF[oi] = z;
          else if constexpr (MODE == 1) outB[oi] = f2bf(z);
          else if constexpr (MODE == 2) outB[oi] = f2bf(tanhf(z));
          else if constexpr (MODE == 3) outB[oi] = f2bf(1.f / (1.f + expf(-z)));
          else if constexpr (MODE == 4) { float m = fmaxf(z, 0.f); outB[oi] = f2bf(m * m); }
          else if constexpr (MODE == 5) { z += bias[col]; outF[oi] = 1.f / (1.f + expf(-z)); }
          else if constexpr (MODE == 6) {
            z += bias[col];
            float sg = 1.f / (1.f + expf(-z));
            outF[oi] = expf(-0.6065306597126334f * sg);
          } else { outF[oi] = z + res[oi]; }
        }
      }
}

// ---------------- K4: kk-normalize, a/b vectors, k update (in place) ----------------
__global__ __launch_bounds__(256) void k4_prep(
    float* __restrict__ k, const float* __restrict__ a,
    const float* __restrict__ kkc, const float* __restrict__ kac,
    float* __restrict__ aw, float* __restrict__ bw) {
  const int row = blockIdx.x, tid = threadIdx.x;
  const int c = tid * 4;
  const size_t base = (size_t)row * Cc + c;
  float k0 = k[base], k1 = k[base + 1], k2 = k[base + 2], k3 = k[base + 3];
  float a0 = a[base], a1 = a[base + 1], a2 = a[base + 2], a3 = a[base + 3];
  float h0 = k0 * kkc[c], h1 = k1 * kkc[c + 1], h2 = k2 * kkc[c + 2], h3 = k3 * kkc[c + 3];
  float ss = h0 * h0 + h1 * h1 + h2 * h2 + h3 * h3;
  #pragma unroll
  for (int m = 8; m; m >>= 1) ss += __shfl_xor(ss, m);
  float inv = 1.f / fmaxf(sqrtf(ss), 1e-12f);
  h0 *= inv; h1 *= inv; h2 *= inv; h3 *= inv;
  float4 v4;
  v4.x = -h0; v4.y = -h1; v4.z = -h2; v4.w = -h3;
  *(float4*)(aw + base) = v4;
  v4.x = h0 * a0; v4.y = h1 * a1; v4.z = h2 * a2; v4.w = h3 * a3;
  *(float4*)(bw + base) = v4;
  v4.x = k0 * (1.f + (a0 - 1.f) * kac[c]);
  v4.y = k1 * (1.f + (a1 - 1.f) * kac[c + 1]);
  v4.z = k2 * (1.f + (a2 - 1.f) * kac[c + 2]);
  v4.w = k3 * (1.f + (a3 - 1.f) * kac[c + 3]);
  *(float4*)(k + base) = v4;
}

// ---------------- K5: WKV7 recurrence — chunked staging + DPP reductions ----------------
// 512 blocks = (rq, bh). Lane = r16*4 + cq (cq in LOW 2 bits): the 4 col-quarter
// partials of one row live in ONE QUAD -> sa/oo reductions are 2 DPP quad_perm
// adds each (pure VALU, ~4 cyc) instead of 2 ds_swizzle ops (~120 cyc LDS
// latency each, 4 per step — the R6 stall path; all bh are parallel so k5
// duration == 512 x per-wave stall path, only shortening it helps).
// Chunked prefetch (CS=8, 12 uint4 regs, no spill) unchanged from R6.
#define CS 8
__global__ __launch_bounds__(64) void k5_wkv7(
    const float* __restrict__ r, const float* __restrict__ dec,
    const float* __restrict__ k, const float* __restrict__ v,
    const float* __restrict__ aw, const float* __restrict__ bw,
    float* __restrict__ o) {
  const int blk = blockIdx.x;          // 0..511
  const int bh = blk & 127, rq = blk >> 7;
  const int b = bh >> 4, h = bh & 15;
  const int lane = threadIdx.x;
  const int cq = lane & 3;             // column quarter (0..3) — quad-local!
  const int r16 = lane >> 2;           // row within quarter (0..15)
  const int row = rq * 16 + r16;       // state row i
  const int cb = cq << 4;              // column base j0

  // chunk layout: [6][CS][64] floats; arrs: a,d,b,k,r,v
  __shared__ float buf[2][6 * CS * 64];

  float S[16];
  #pragma unroll
  for (int j = 0; j < 16; ++j) S[j] = 0.f;

  const size_t base = (size_t)b * Tt * Cc + (size_t)h * Nh;
  const int loff = ((lane >> 4) << 10) + ((lane & 15) << 2);
  const int soff = lane << 2;

  uint4 R[12];
  #define LOADC(cstart) { \
    const size_t g0 = base + (size_t)(cstart) * Cc + loff; \
    _Pragma("unroll") \
    for (int sg = 0; sg < 2; ++sg) { \
      R[0 * 2 + sg] = *(const uint4*)(aw  + g0 + sg * 4096); \
      R[1 * 2 + sg] = *(const uint4*)(dec + g0 + sg * 4096); \
      R[2 * 2 + sg] = *(const uint4*)(bw  + g0 + sg * 4096); \
      R[3 * 2 + sg] = *(const uint4*)(k   + g0 + sg * 4096); \
      R[4 * 2 + sg] = *(const uint4*)(r   + g0 + sg * 4096); \
      R[5 * 2 + sg] = *(const uint4*)(v   + g0 + sg * 4096); \
    } }

  LOADC(0)

  #pragma unroll 1
  for (int c = 0; c < Tt / CS; ++c) {
    float* bp = buf[c & 1];
    #pragma unroll
    for (int arr = 0; arr < 6; ++arr)
      #pragma unroll
      for (int sg = 0; sg < 2; ++sg)
        *(uint4*)(bp + arr * (CS * 64) + sg * 256 + soff) = R[arr * 2 + sg];
    const int cn = (c + 1 < Tt / CS) ? (c + 1) : c;
    LOADC(cn * CS)
    #pragma unroll 2
    for (int s = 0; s < CS; ++s) {
      const int t = c * CS + s;
      const float* sp = bp + s * 64;
      const float* ap  = sp + cb;
      const float* dp  = sp + 1 * (CS * 64) + cb;
      const float* bpp = sp + 2 * (CS * 64) + cb;
      const float* kp  = sp + 3 * (CS * 64) + cb;
      const float* rp  = sp + 4 * (CS * 64) + cb;
      const float  vv  = sp[5 * (CS * 64) + row];

      float sa0 = 0.f, sa1 = 0.f, sa2 = 0.f, sa3 = 0.f;
      #pragma unroll
      for (int jj = 0; jj < 16; jj += 4) {
        float4 a4 = *(const float4*)(ap + jj);
        sa0 = fmaf(S[jj + 0], a4.x, sa0);
        sa1 = fmaf(S[jj + 1], a4.y, sa1);
        sa2 = fmaf(S[jj + 2], a4.z, sa2);
        sa3 = fmaf(S[jj + 3], a4.w, sa3);
      }
      float sa = (sa0 + sa1) + (sa2 + sa3);
      sa = dppadd<0xB1>(sa);   // + lane^1
      sa = dppadd<0x4E>(sa);   // + lane^2

      float o0 = 0.f, o1 = 0.f, o2 = 0.f, o3 = 0.f;
      #pragma unroll
      for (int jj = 0; jj < 16; jj += 4) {
        float4 d4 = *(const float4*)(dp + jj);
        float4 b4 = *(const float4*)(bpp + jj);
        float4 k4 = *(const float4*)(kp + jj);
        float4 r4 = *(const float4*)(rp + jj);
        S[jj + 0] = fmaf(S[jj + 0], d4.x, fmaf(vv, k4.x, sa * b4.x));
        o0 = fmaf(S[jj + 0], r4.x, o0);
        S[jj + 1] = fmaf(S[jj + 1], d4.y, fmaf(vv, k4.y, sa * b4.y));
        o1 = fmaf(S[jj + 1], r4.y, o1);
        S[jj + 2] = fmaf(S[jj + 2], d4.z, fmaf(vv, k4.z, sa * b4.z));
        o2 = fmaf(S[jj + 2], r4.z, o2);
        S[jj + 3] = fmaf(S[jj + 3], d4.w, fmaf(vv, k4.w, sa * b4.w));
        o3 = fmaf(S[jj + 3], r4.w, o3);
      }
      float oo = (o0 + o1) + (o2 + o3);
      oo = dppadd<0xB1>(oo);
      oo = dppadd<0x4E>(oo);
      if (cq == 0) o[base + (size_t)t * Cc + row] = oo;
    }
  }
  #undef LOADC
}

// ---------------- K6: head GroupNorm + rk bonus + gate ----------------
__global__ __launch_bounds__(256) void k6_out(
    const float* __restrict__ o, const float* __restrict__ r, const float* __restrict__ k,
    const float* __restrict__ v, const float* __restrict__ rk,
    const float* __restrict__ gnw, const float* __restrict__ gnb,
    const float* __restrict__ g, unsigned short* __restrict__ og) {
  const int row = blockIdx.x, tid = threadIdx.x;
  const int c = tid * 4;
  const size_t base = (size_t)row * Cc + c;
  float o0 = o[base], o1 = o[base + 1], o2 = o[base + 2], o3 = o[base + 3];
  float r0 = r[base], r1 = r[base + 1], r2 = r[base + 2], r3 = r[base + 3];
  float k0 = k[base], k1 = k[base + 1], k2 = k[base + 2], k3 = k[base + 3];
  float s = o0 + o1 + o2 + o3;
  float q = o0 * o0 + o1 * o1 + o2 * o2 + o3 * o3;
  float bs = r0 * k0 * rk[c] + r1 * k1 * rk[c + 1] + r2 * k2 * rk[c + 2] + r3 * k3 * rk[c + 3];
  #pragma unroll
  for (int m = 8; m; m >>= 1) {
    s += __shfl_xor(s, m); q += __shfl_xor(q, m); bs += __shfl_xor(bs, m);
  }
  float mu = s * (1.f / 64.f);
  float var = q * (1.f / 64.f) - mu * mu;
  float rs = rsqrtf(var + 64e-5f);
  float v0 = v[base], v1 = v[base + 1], v2 = v[base + 2], v3 = v[base + 3];
  float z0 = (o0 - mu) * rs * gnw[c] + gnb[c] + bs * v0;
  float z1 = (o1 - mu) * rs * gnw[c + 1] + gnb[c + 1] + bs * v1;
  float z2 = (o2 - mu) * rs * gnw[c + 2] + gnb[c + 2] + bs * v2;
  float z3 = (o3 - mu) * rs * gnw[c + 3] + gnb[c + 3] + bs * v3;
  ushort4 u;
  u.x = f2bf(z0 * g[base]); u.y = f2bf(z1 * g[base + 1]);
  u.z = f2bf(z2 * g[base + 2]); u.w = f2bf(z3 * g[base + 3]);
  *(ushort4*)(og + base) = u;
}

// ---------------- K8: FFN LN + time-shift mix ----------------
__global__ __launch_bounds__(256) void k8_ffnmix(
    const float* __restrict__ x2, const float* __restrict__ lnw, const float* __restrict__ lnb,
    const float* __restrict__ fxk, unsigned short* __restrict__ kf) {
  __shared__ float red[8];
  const int row = blockIdx.x;
  const int t = row & (Tt - 1);
  const int tid = threadIdx.x;
  const int c = tid * 4;
  const size_t base = (size_t)row * Cc + c;
  float a0 = x2[base], a1 = x2[base + 1], a2 = x2[base + 2], a3 = x2[base + 3];
  float mu, rs;
  row_stats(a0, a1, a2, a3, red, mu, rs, 1e-5f);
  float w0 = lnw[c], w1 = lnw[c + 1], w2 = lnw[c + 2], w3 = lnw[c + 3];
  float b0 = lnb[c], b1 = lnb[c + 1], b2 = lnb[c + 2], b3 = lnb[c + 3];
  float f0 = (a0 - mu) * rs * w0 + b0, f1 = (a1 - mu) * rs * w1 + b1;
  float f2 = (a2 - mu) * rs * w2 + b2, f3 = (a3 - mu) * rs * w3 + b3;
  float p0 = 0.f, p1 = 0.f, p2 = 0.f, p3 = 0.f;
  if (t > 0) {
    const size_t pb_ = base - Cc;
    float q0 = x2[pb_], q1 = x2[pb_ + 1], q2 = x2[pb_ + 2], q3 = x2[pb_ + 3];
    row_stats(q0, q1, q2, q3, red, mu, rs, 1e-5f);
    p0 = (q0 - mu) * rs * w0 + b0; p1 = (q1 - mu) * rs * w1 + b1;
    p2 = (q2 - mu) * rs * w2 + b2; p3 = (q3 - mu) * rs * w3 + b3;
  }
  ushort4 u;
  u.x = f2bf(f0 + (p0 - f0) * fxk[c]);
  u.y = f2bf(f1 + (p1 - f1) * fxk[c + 1]);
  u.z = f2bf(f2 + (p2 - f2) * fxk[c + 2]);
  u.w = f2bf(f3 + (p3 - f3) * fxk[c + 3]);
  *(ushort4*)(kf + base) = u;
}

// ---------------- host ----------------
extern "C" void kernel_launch(void* const* d_in, const int* in_sizes, int n_in,
                              void* d_out, int out_size, void* d_ws, size_t ws_size,
                              hipStream_t stream) {
  (void)in_sizes; (void)n_in; (void)out_size; (void)ws_size;
  const float* x    = (const float*)d_in[0];
  const float* lnpw = (const float*)d_in[2];
  const float* lnpb = (const float*)d_in[3];
  const float* lnaw = (const float*)d_in[4];
  const float* lnab = (const float*)d_in[5];
  const float* lnfw = (const float*)d_in[6];
  const float* lnfb = (const float*)d_in[7];
  const float* cxr  = (const float*)d_in[8];
  const float* cxw  = (const float*)d_in[9];
  const float* cxk  = (const float*)d_in[10];
  const float* cxv  = (const float*)d_in[11];
  const float* cxa  = (const float*)d_in[12];
  const float* cxg  = (const float*)d_in[13];
  const float* w0v  = (const float*)d_in[14];
  const float* w1m  = (const float*)d_in[15];
  const float* w2m  = (const float*)d_in[16];
  const float* a0v  = (const float*)d_in[17];
  const float* a1m  = (const float*)d_in[18];
  const float* a2m  = (const float*)d_in[19];
  const float* g1m  = (const float*)d_in[20];
  const float* g2m  = (const float*)d_in[21];
  const float* kkv  = (const float*)d_in[22];
  const float* kav  = (const float*)d_in[23];
  const float* rkv  = (const float*)d_in[24];
  const float* Wr   = (const float*)d_in[25];
  const float* Wk   = (const float*)d_in[26];
  const float* Wv   = (const float*)d_in[27];
  const float* Wo   = (const float*)d_in[28];
  const float* gnw  = (const float*)d_in[29];
  const float* gnb  = (const float*)d_in[30];
  const float* fxk  = (const float*)d_in[31];
  const float* Wf1  = (const float*)d_in[32];
  const float* Wf2  = (const float*)d_in[33];

  char* ws = (char*)d_ws;
  float* outx = (float*)d_out;          // final x (B,T,C)
  float* vout = outx + BTC;             // v_first = v (B,T,C)

  // workspace layout (all offsets multiples of big pow2; aliases noted)
  size_t off = 0;
  unsigned short* WrT  = (unsigned short*)(ws + off); off += 2097152;
  unsigned short* WkT  = (unsigned short*)(ws + off); off += 2097152;
  unsigned short* WvT  = (unsigned short*)(ws + off); off += 2097152;
  unsigned short* WoT  = (unsigned short*)(ws + off); off += 2097152;
  unsigned short* Wf1T = (unsigned short*)(ws + off); off += 8388608;
  unsigned short* Wf2T = (unsigned short*)(ws + off); off += 8388608;
  unsigned short* w1T  = (unsigned short*)(ws + off); off += 131072;
  unsigned short* w2T  = (unsigned short*)(ws + off); off += 131072;
  unsigned short* a1T  = (unsigned short*)(ws + off); off += 131072;
  unsigned short* a2T  = (unsigned short*)(ws + off); off += 131072;
  unsigned short* g1T  = (unsigned short*)(ws + off); off += 262144;
  unsigned short* g2T  = (unsigned short*)(ws + off); off += 262144;
  float* xln = (float*)(ws + off); off += 16777216;
  unsigned short* mixR = (unsigned short*)(ws + off);          // 6 x 8388608
  unsigned short* mixW = (unsigned short*)(ws + off + 8388608);
  unsigned short* mixK = (unsigned short*)(ws + off + 16777216);
  unsigned short* mixV = (unsigned short*)(ws + off + 25165824);
  unsigned short* mixA = (unsigned short*)(ws + off + 33554432);
  unsigned short* mixG = (unsigned short*)(ws + off + 41943040);
  unsigned short* hbuf = (unsigned short*)(ws + off);          // alias mix (dead by then)
  off += 50331648;
  unsigned short* tmpw = (unsigned short*)(ws + off); off += 524288;
  unsigned short* tmpa = (unsigned short*)(ws + off); off += 524288;
  unsigned short* tmpg = (unsigned short*)(ws + off); off += 1048576;
  float* decay = (float*)(ws + off);
  unsigned short* og = (unsigned short*)(ws + off);            // alias decay (dead after K5)
  off += 16777216;
  float* aicl = (float*)(ws + off);
  float* obuf = (float*)(ws + off);                            // alias aicl (dead after K4)
  off += 16777216;
  float* gout = (float*)(ws + off); off += 16777216;
  float* rbuf = (float*)(ws + off);
  float* x2   = (float*)(ws + off);                            // alias rbuf (dead after K6)
  off += 16777216;
  float* kbuf = (float*)(ws + off); off += 16777216;
  float* awb  = (float*)(ws + off);
  unsigned short* kf = (unsigned short*)(ws + off);            // alias awb (dead after K5)
  off += 16777216;
  float* bwb  = (float*)(ws + off); off += 16777216;           // total ~187 MB

  dim3 tb(32, 8);
  // weight prep: f32 (K,N) -> bf16 (N,K)
  kt_transpose<<<dim3(32, 32), tb, 0, stream>>>(Wr, WrT, 1024, 1024);
  kt_transpose<<<dim3(32, 32), tb, 0, stream>>>(Wk, WkT, 1024, 1024);
  kt_transpose<<<dim3(32, 32), tb, 0, stream>>>(Wv, WvT, 1024, 1024);
  kt_transpose<<<dim3(32, 32), tb, 0, stream>>>(Wo, WoT, 1024, 1024);
  kt_transpose<<<dim3(128, 32), tb, 0, stream>>>(Wf1, Wf1T, 1024, 4096);
  kt_transpose<<<dim3(32, 128), tb, 0, stream>>>(Wf2, Wf2T, 4096, 1024);
  kt_transpose<<<dim3(2, 32), tb, 0, stream>>>(w1m, w1T, 1024, 64);
  kt_transpose<<<dim3(32, 2), tb, 0, stream>>>(w2m, w2T, 64, 1024);
  kt_transpose<<<dim3(2, 32), tb, 0, stream>>>(a1m, a1T, 1024, 64);
  kt_transpose<<<dim3(32, 2), tb, 0, stream>>>(a2m, a2T, 64, 1024);
  kt_transpose<<<dim3(4, 32), tb, 0, stream>>>(g1m, g1T, 1024, 128);
  kt_transpose<<<dim3(32, 4), tb, 0, stream>>>(g2m, g2T, 128, 1024);

  // K1: pre-LN + attn-LN + shift mixes
  k1_mix<<<Mm, 256, 0, stream>>>(x, lnpw, lnpb, lnaw, lnab, cxr, cxw, cxk, cxv, cxa, cxg,
                                 xln, mixR, mixW, mixK, mixV, mixA, mixG);

  // LoRA chains
  kg_gemm<2><<<dim3(1, 32), 256, 0, stream>>>(mixW, w1T, Mm, 64, 1024, nullptr, tmpw, nullptr, nullptr);
  kg_gemm<6><<<dim3(8, 32), 256, 0, stream>>>(tmpw, w2T, Mm, 1024, 64, decay, nullptr, w0v, nullptr);
  kg_gemm<1><<<dim3(1, 32), 256, 0, stream>>>(mixA, a1T, Mm, 64, 1024, nullptr, tmpa, nullptr, nullptr);
  kg_gemm<5><<<dim3(8, 32), 256, 0, stream>>>(tmpa, a2T, Mm, 1024, 64, aicl, nullptr, a0v, nullptr);
  kg_gemm<3><<<dim3(1, 32), 256, 0, stream>>>(mixG, g1T, Mm, 128, 1024, nullptr, tmpg, nullptr, nullptr);
  kg_gemm<0><<<dim3(8, 32), 256, 0, stream>>>(tmpg, g2T, Mm, 1024, 128, gout, nullptr, nullptr, nullptr);

  // r / k / v projections (v straight into d_out as v_first)
  kg_gemm<0><<<dim3(8, 32), 256, 0, stream>>>(mixR, WrT, Mm, 1024, 1024, rbuf, nullptr, nullptr, nullptr);
  kg_gemm<0><<<dim3(8, 32), 256, 0, stream>>>(mixK, WkT, Mm, 1024, 1024, kbuf, nullptr, nullptr, nullptr);
  kg_gemm<0><<<dim3(8, 32), 256, 0, stream>>>(mixV, WvT, Mm, 1024, 1024, vout, nullptr, nullptr, nullptr);

  // recurrence inputs
  k4_prep<<<Mm, 256, 0, stream>>>(kbuf, aicl, kkv, kav, awb, bwb);
  // WKV7 scan: 512 blocks = (rq, bh), chunked LDS staging + DPP reductions
  k5_wkv7<<<512, 64, 0, stream>>>(rbuf, decay, kbuf, vout, awb, bwb, obuf);
  // GN + bonus + gate
  k6_out<<<Mm, 256, 0, stream>>>(obuf, rbuf, kbuf, vout, rkv, gnw, gnb, gout, og);
  // o-projection + residual -> x2
  kg_gemm<7><<<dim3(8, 32), 256, 0, stream>>>(og, WoT, Mm, 1024, 1024, x2, nullptr, nullptr, xln);
  // FFN
  k8_ffnmix<<<Mm, 256, 0, stream>>>(x2, lnfw, lnfb, fxk, kf);
  kg_gemm<4><<<dim3(32, 32), 256, 0, stream>>>(kf, Wf1T, Mm, 4096, 1024, nullptr, hbuf, nullptr, nullptr);
  kg_gemm<7><<<dim3(8, 32), 256, 0, stream>>>(hbuf, Wf2T, Mm, 1024, 4096, outx, nullptr, nullptr, x2);
}

// Round 8
// 824.113 us; speedup vs baseline: 1.3950x; 1.1369x over previous
//
#include <hip/hip_runtime.h>

// ---------------- constants ----------------
#define Bb 8
#define Tt 512
#define Cc 1024
#define Hh 16
#define Nh 64
#define Mm 4096            // B*T
#define BTC 4194304        // M*C
#define DEV __device__ __forceinline__

typedef __attribute__((ext_vector_type(8))) short short8;
typedef __attribute__((ext_vector_type(4))) float f32x4;

DEV unsigned short f2bf(float f) {
  unsigned int u = __builtin_bit_cast(unsigned int, f);
  u += 0x7fffu + ((u >> 16) & 1u);
  return (unsigned short)(u >> 16);
}

// quad_perm butterfly add via DPP — pure VALU. 0xB1=xor1, 0x4E=xor2
template <int CTRL>
DEV float dppadd(float x) {
  int xi = __builtin_bit_cast(int, x);
  int yi = __builtin_amdgcn_update_dpp(0, xi, CTRL, 0xF, 0xF, true);
  return x + __builtin_bit_cast(float, yi);
}

// ---------------- transpose f32 (K x N) -> bf16 (N x K) ----------------
__global__ __launch_bounds__(256) void kt_transpose(const float* __restrict__ in,
                                                    unsigned short* __restrict__ out,
                                                    int K, int N) {
  __shared__ float tile[32][33];
  int bx = blockIdx.x * 32;
  int by = blockIdx.y * 32;
  int tx = threadIdx.x, ty = threadIdx.y;
  #pragma unroll
  for (int i = ty; i < 32; i += 8) {
    int kk = by + i, nn = bx + tx;
    tile[i][tx] = (kk < K && nn < N) ? in[(size_t)kk * N + nn] : 0.f;
  }
  __syncthreads();
  #pragma unroll
  for (int i = ty; i < 32; i += 8) {
    int nn = bx + i, kk = by + tx;
    if (nn < N && kk < K) out[(size_t)nn * K + kk] = f2bf(tile[tx][i]);
  }
}

// batched square 1024x1024 transpose: z selects among 4 matrices
__global__ __launch_bounds__(256) void kt_transpose4(
    const float* __restrict__ i0, const float* __restrict__ i1,
    const float* __restrict__ i2, const float* __restrict__ i3,
    unsigned short* __restrict__ o0, unsigned short* __restrict__ o1,
    unsigned short* __restrict__ o2, unsigned short* __restrict__ o3) {
  __shared__ float tile[32][33];
  const float* in = blockIdx.z == 0 ? i0 : blockIdx.z == 1 ? i1 : blockIdx.z == 2 ? i2 : i3;
  unsigned short* out = blockIdx.z == 0 ? o0 : blockIdx.z == 1 ? o1 : blockIdx.z == 2 ? o2 : o3;
  int bx = blockIdx.x * 32, by = blockIdx.y * 32;
  int tx = threadIdx.x, ty = threadIdx.y;
  #pragma unroll
  for (int i = ty; i < 32; i += 8)
    tile[i][tx] = in[(size_t)(by + i) * 1024 + bx + tx];
  __syncthreads();
  #pragma unroll
  for (int i = ty; i < 32; i += 8)
    out[(size_t)(bx + i) * 1024 + by + tx] = f2bf(tile[tx][i]);
}

// ---------------- block row stats (1024 elems over 256 threads) ----------------
DEV void row_stats(float v0, float v1, float v2, float v3, float* red,
                   float& mu, float& rs, float eps) {
  float s = v0 + v1 + v2 + v3;
  float q = v0 * v0 + v1 * v1 + v2 * v2 + v3 * v3;
  #pragma unroll
  for (int o = 32; o; o >>= 1) { s += __shfl_down(s, o); q += __shfl_down(q, o); }
  int w = threadIdx.x >> 6;
  __syncthreads();
  if ((threadIdx.x & 63) == 0) { red[w] = s; red[4 + w] = q; }
  __syncthreads();
  s = red[0] + red[1] + red[2] + red[3];
  q = red[4] + red[5] + red[6] + red[7];
  mu = s * (1.f / 1024.f);
  float var = q * (1.f / 1024.f) - mu * mu;
  rs = rsqrtf(var + eps);
}

// ---------------- K1: pre-LN + attn-LN + time-shift mixes ----------------
__global__ __launch_bounds__(256) void k1_mix(
    const float* __restrict__ x,
    const float* __restrict__ lnpw, const float* __restrict__ lnpb,
    const float* __restrict__ lnaw, const float* __restrict__ lnab,
    const float* __restrict__ cr, const float* __restrict__ cw,
    const float* __restrict__ ck, const float* __restrict__ cv,
    const float* __restrict__ ca, const float* __restrict__ cg,
    float* __restrict__ xln,
    unsigned short* __restrict__ mR, unsigned short* __restrict__ mW,
    unsigned short* __restrict__ mK, unsigned short* __restrict__ mV,
    unsigned short* __restrict__ mA, unsigned short* __restrict__ mG) {
  __shared__ float red[8];
  const int row = blockIdx.x;
  const int t = row & (Tt - 1);
  const int tid = threadIdx.x;
  const int c = tid * 4;
  const size_t base = (size_t)row * Cc + c;
  float a0 = x[base], a1 = x[base + 1], a2 = x[base + 2], a3 = x[base + 3];
  float mu, rs;
  row_stats(a0, a1, a2, a3, red, mu, rs, 1e-5f);
  float pw0 = lnpw[c], pw1 = lnpw[c + 1], pw2 = lnpw[c + 2], pw3 = lnpw[c + 3];
  float pb0 = lnpb[c], pb1 = lnpb[c + 1], pb2 = lnpb[c + 2], pb3 = lnpb[c + 3];
  float l0 = (a0 - mu) * rs * pw0 + pb0, l1 = (a1 - mu) * rs * pw1 + pb1;
  float l2 = (a2 - mu) * rs * pw2 + pb2, l3 = (a3 - mu) * rs * pw3 + pb3;
  float4 st; st.x = l0; st.y = l1; st.z = l2; st.w = l3;
  *(float4*)(xln + base) = st;
  row_stats(l0, l1, l2, l3, red, mu, rs, 1e-5f);
  float aw0 = lnaw[c], aw1 = lnaw[c + 1], aw2 = lnaw[c + 2], aw3 = lnaw[c + 3];
  float ab0 = lnab[c], ab1 = lnab[c + 1], ab2 = lnab[c + 2], ab3 = lnab[c + 3];
  float n0 = (l0 - mu) * rs * aw0 + ab0, n1 = (l1 - mu) * rs * aw1 + ab1;
  float n2 = (l2 - mu) * rs * aw2 + ab2, n3 = (l3 - mu) * rs * aw3 + ab3;
  float p0 = 0.f, p1 = 0.f, p2 = 0.f, p3 = 0.f;
  if (t > 0) {  // uniform over block
    const size_t pb_ = base - Cc;
    float q0 = x[pb_], q1 = x[pb_ + 1], q2 = x[pb_ + 2], q3 = x[pb_ + 3];
    row_stats(q0, q1, q2, q3, red, mu, rs, 1e-5f);
    float e0 = (q0 - mu) * rs * pw0 + pb0, e1 = (q1 - mu) * rs * pw1 + pb1;
    float e2 = (q2 - mu) * rs * pw2 + pb2, e3 = (q3 - mu) * rs * pw3 + pb3;
    row_stats(e0, e1, e2, e3, red, mu, rs, 1e-5f);
    p0 = (e0 - mu) * rs * aw0 + ab0; p1 = (e1 - mu) * rs * aw1 + ab1;
    p2 = (e2 - mu) * rs * aw2 + ab2; p3 = (e3 - mu) * rs * aw3 + ab3;
  }
  float d0 = p0 - n0, d1 = p1 - n1, d2 = p2 - n2, d3 = p3 - n3;
  #define EMIT(cf, dst) { \
    float f0 = cf[c], f1 = cf[c + 1], f2 = cf[c + 2], f3 = cf[c + 3]; \
    ushort4 u; u.x = f2bf(n0 + d0 * f0); u.y = f2bf(n1 + d1 * f1); \
    u.z = f2bf(n2 + d2 * f2); u.w = f2bf(n3 + d3 * f3); \
    *(ushort4*)(dst + base) = u; }
  EMIT(cr, mR) EMIT(cw, mW) EMIT(ck, mK) EMIT(cv, mV) EMIT(ca, mA) EMIT(cg, mG)
  #undef EMIT
}

// ---------------- 128x64 bf16 MFMA GEMM (m97-style staging) ----------------
// 128M x 64N tiles -> 2x the blocks of the 128x128 version: for N=1024 grids
// go 256->512 blocks = 2/CU so the vmcnt(0) barrier drain of one block hides
// behind the other's MFMA (R7 pathology: 1 block/CU, nothing to overlap).
// A: (M,K) bf16 row-major; Bt: (N,K) bf16 row-major.
// MODE: 0 f32 | 1 bf16 | 2 tanh->bf16 | 3 sigmoid->bf16 | 4 relu^2->bf16
//       5 sigmoid(z+bias[col])->f32 | 6 exp(-sigmoid(z+bias[col])*e^-.5)->f32 | 7 z+res->f32
DEV void gll16(const unsigned short* g, unsigned short* l) {
  __builtin_amdgcn_global_load_lds(
      (const __attribute__((address_space(1))) void*)g,
      (__attribute__((address_space(3))) void*)l, 16, 0, 0);
}

template <int MODE>
__global__ __launch_bounds__(256) void kg_gemm(
    const unsigned short* __restrict__ A, const unsigned short* __restrict__ Bt,
    int M, int Nn, int K,
    float* __restrict__ outF, unsigned short* __restrict__ outB,
    const float* __restrict__ bias, const float* __restrict__ res) {
  __shared__ unsigned short lsA[128 * 32];
  __shared__ unsigned short lsB[64 * 32];
  const int tid = threadIdx.x;
  const int lane = tid & 63;
  const int wave = tid >> 6;
  const int wy = wave >> 1, wx = wave & 1;
  const int m0 = blockIdx.y * 128;
  const int n0 = blockIdx.x * 64;
  const int sl4 = lane >> 2;        // row within 16-row group
  const int sc = (lane & 3) << 3;   // k-elem offset {0,8,16,24}
  f32x4 acc[4][2];
  #pragma unroll
  for (int i = 0; i < 4; ++i)
    #pragma unroll
    for (int j = 0; j < 2; ++j) { f32x4 z = {0.f, 0.f, 0.f, 0.f}; acc[i][j] = z; }
  const int fr = lane & 15;
  const int fk = (lane >> 4) << 3;
  for (int k0 = 0; k0 < K; k0 += 32) {
    #pragma unroll
    for (int j = 0; j < 2; ++j) {        // A: 8 groups of 16 rows, wave does 2
      const int rb = (wave + j * 4) * 16;
      gll16(A + (size_t)(m0 + rb + sl4) * K + k0 + sc, lsA + rb * 32);
    }
    {                                    // B: 4 groups, wave does 1
      const int rb = wave * 16;
      int br = n0 + rb + sl4;
      br = br < Nn ? br : Nn - 1;
      gll16(Bt + (size_t)br * K + k0 + sc, lsB + rb * 32);
    }
    __syncthreads();
    short8 af[4], bf[2];
    #pragma unroll
    for (int mt = 0; mt < 4; ++mt)
      af[mt] = *(const short8*)(lsA + (wy * 64 + mt * 16 + fr) * 32 + fk);
    #pragma unroll
    for (int nt = 0; nt < 2; ++nt)
      bf[nt] = *(const short8*)(lsB + (wx * 32 + nt * 16 + fr) * 32 + fk);
    #pragma unroll
    for (int mt = 0; mt < 4; ++mt)
      #pragma unroll
      for (int nt = 0; nt < 2; ++nt)
        acc[mt][nt] = __builtin_amdgcn_mfma_f32_16x16x32_bf16(af[mt], bf[nt], acc[mt][nt], 0, 0, 0);
    __syncthreads();
  }
  const int rbase = (lane >> 4) << 2;
  const int cbase = lane & 15;
  #pragma unroll
  for (int mt = 0; mt < 4; ++mt)
    #pragma unroll
    for (int nt = 0; nt < 2; ++nt)
      #pragma unroll
      for (int rr = 0; rr < 4; ++rr) {
        int row = m0 + wy * 64 + mt * 16 + rbase + rr;
        int col = n0 + wx * 32 + nt * 16 + cbase;
        if (col < Nn) {
          size_t oi = (size_t)row * Nn + col;
          float z = acc[mt][nt][rr];
          if constexpr (MODE == 0) outF[oi] = z;
          else if constexpr (MODE == 1) outB[oi] = f2bf(z);
          else if constexpr (MODE == 2) outB[oi] = f2bf(tanhf(z));
          else if constexpr (MODE == 3) outB[oi] = f2bf(1.f / (1.f + expf(-z)));
          else if constexpr (MODE == 4) { float m = fmaxf(z, 0.f); outB[oi] = f2bf(m * m); }
          else if constexpr (MODE == 5) { z += bias[col]; outF[oi] = 1.f / (1.f + expf(-z)); }
          else if constexpr (MODE == 6) {
            z += bias[col];
            float sg = 1.f / (1.f + expf(-z));
            outF[oi] = expf(-0.6065306597126334f * sg);
          } else { outF[oi] = z + res[oi]; }
        }
      }
}

// ---------------- K4: kk-normalize, a/b vectors, k update (in place) ----------------
__global__ __launch_bounds__(256) void k4_prep(
    float* __restrict__ k, const float* __restrict__ a,
    const float* __restrict__ kkc, const float* __restrict__ kac,
    float* __restrict__ aw, float* __restrict__ bw) {
  const int row = blockIdx.x, tid = threadIdx.x;
  const int c = tid * 4;
  const size_t base = (size_t)row * Cc + c;
  float k0 = k[base], k1 = k[base + 1], k2 = k[base + 2], k3 = k[base + 3];
  float a0 = a[base], a1 = a[base + 1], a2 = a[base + 2], a3 = a[base + 3];
  float h0 = k0 * kkc[c], h1 = k1 * kkc[c + 1], h2 = k2 * kkc[c + 2], h3 = k3 * kkc[c + 3];
  float ss = h0 * h0 + h1 * h1 + h2 * h2 + h3 * h3;
  #pragma unroll
  for (int m = 8; m; m >>= 1) ss += __shfl_xor(ss, m);
  float inv = 1.f / fmaxf(sqrtf(ss), 1e-12f);
  h0 *= inv; h1 *= inv; h2 *= inv; h3 *= inv;
  float4 v4;
  v4.x = -h0; v4.y = -h1; v4.z = -h2; v4.w = -h3;
  *(float4*)(aw + base) = v4;
  v4.x = h0 * a0; v4.y = h1 * a1; v4.z = h2 * a2; v4.w = h3 * a3;
  *(float4*)(bw + base) = v4;
  v4.x = k0 * (1.f + (a0 - 1.f) * kac[c]);
  v4.y = k1 * (1.f + (a1 - 1.f) * kac[c + 1]);
  v4.z = k2 * (1.f + (a2 - 1.f) * kac[c + 2]);
  v4.w = k3 * (1.f + (a3 - 1.f) * kac[c + 3]);
  *(float4*)(k + base) = v4;
}

// ---------------- K5: WKV7 — chunked staging + DPP + register pipeline ----------------
// 512 blocks = (rq, bh); lane = r16*4 + cq; S in 16 VGPRs. Chunked global
// prefetch (CS=8, R6/R7 structure). NEW: the 8-step body is fully unrolled with
// explicit double-buffered operand registers — step s+1's 21 LDS vectors load
// while step s computes. R7 pathology: VGPR=88 gave the scheduler no headroom
// to hoist ds_reads across steps, exposing ~21x LDS latency per step.
// __launch_bounds__(64,1): allow ~240 VGPRs (1 wave/block; occupancy moot).
#define CS 8
__global__ __launch_bounds__(64, 1) void k5_wkv7(
    const float* __restrict__ r, const float* __restrict__ dec,
    const float* __restrict__ k, const float* __restrict__ v,
    const float* __restrict__ aw, const float* __restrict__ bw,
    float* __restrict__ o) {
  const int blk = blockIdx.x;          // 0..511
  const int bh = blk & 127, rq = blk >> 7;
  const int b = bh >> 4, h = bh & 15;
  const int lane = threadIdx.x;
  const int cq = lane & 3;             // column quarter — quad-local
  const int r16 = lane >> 2;           // row within quarter
  const int row = rq * 16 + r16;       // state row i
  const int cb = cq << 4;              // column base j0

  __shared__ float buf[2][6 * CS * 64];   // [a|d|b|k|r|v][CS][64]

  float S[16];
  #pragma unroll
  for (int j = 0; j < 16; ++j) S[j] = 0.f;

  const size_t base = (size_t)b * Tt * Cc + (size_t)h * Nh;
  const int loff = ((lane >> 4) << 10) + ((lane & 15) << 2);
  const int soff = lane << 2;

  uint4 R[12];
  #define LOADC(cstart) { \
    const size_t g0 = base + (size_t)(cstart) * Cc + loff; \
    _Pragma("unroll") \
    for (int sg = 0; sg < 2; ++sg) { \
      R[0 * 2 + sg] = *(const uint4*)(aw  + g0 + sg * 4096); \
      R[1 * 2 + sg] = *(const uint4*)(dec + g0 + sg * 4096); \
      R[2 * 2 + sg] = *(const uint4*)(bw  + g0 + sg * 4096); \
      R[3 * 2 + sg] = *(const uint4*)(k   + g0 + sg * 4096); \
      R[4 * 2 + sg] = *(const uint4*)(r   + g0 + sg * 4096); \
      R[5 * 2 + sg] = *(const uint4*)(v   + g0 + sg * 4096); \
    } }

  LOADC(0)

  #pragma unroll 1
  for (int c = 0; c < Tt / CS; ++c) {
    float* bp = buf[c & 1];
    #pragma unroll
    for (int arr = 0; arr < 6; ++arr)
      #pragma unroll
      for (int sg = 0; sg < 2; ++sg)
        *(uint4*)(bp + arr * (CS * 64) + sg * 256 + soff) = R[arr * 2 + sg];
    const int cn = (c + 1 < Tt / CS) ? (c + 1) : c;
    LOADC(cn * CS)

    // operand register double-buffer
    float4 Aq[2][4], Dq[2][4], Bq[2][4], Kq[2][4], Rq[2][4];
    float Vv[2];
    #define LOADOPS(slot, ss) { \
      const float* sp_ = bp + (ss) * 64; \
      _Pragma("unroll") \
      for (int i = 0; i < 4; ++i) { \
        Aq[slot][i] = *(const float4*)(sp_ + cb + i * 4); \
        Dq[slot][i] = *(const float4*)(sp_ + 512 + cb + i * 4); \
        Bq[slot][i] = *(const float4*)(sp_ + 1024 + cb + i * 4); \
        Kq[slot][i] = *(const float4*)(sp_ + 1536 + cb + i * 4); \
        Rq[slot][i] = *(const float4*)(sp_ + 2048 + cb + i * 4); \
      } \
      Vv[slot] = sp_[2560 + row]; }

    LOADOPS(0, 0)
    #pragma unroll
    for (int s = 0; s < CS; ++s) {
      const int cu = s & 1, nx = cu ^ 1;
      if (s + 1 < CS) LOADOPS(nx, s + 1)     // prefetch next step's operands

      float sa0 = 0.f, sa1 = 0.f, sa2 = 0.f, sa3 = 0.f;
      #pragma unroll
      for (int i = 0; i < 4; ++i) {
        float4 a4 = Aq[cu][i];
        sa0 = fmaf(S[i * 4 + 0], a4.x, sa0);
        sa1 = fmaf(S[i * 4 + 1], a4.y, sa1);
        sa2 = fmaf(S[i * 4 + 2], a4.z, sa2);
        sa3 = fmaf(S[i * 4 + 3], a4.w, sa3);
      }
      float sa = (sa0 + sa1) + (sa2 + sa3);
      sa = dppadd<0xB1>(sa);
      sa = dppadd<0x4E>(sa);

      const float vv = Vv[cu];
      float o0 = 0.f, o1 = 0.f, o2 = 0.f, o3 = 0.f;
      #pragma unroll
      for (int i = 0; i < 4; ++i) {
        float4 d4 = Dq[cu][i], b4 = Bq[cu][i], k4 = Kq[cu][i], r4 = Rq[cu][i];
        S[i * 4 + 0] = fmaf(S[i * 4 + 0], d4.x, fmaf(vv, k4.x, sa * b4.x));
        o0 = fmaf(S[i * 4 + 0], r4.x, o0);
        S[i * 4 + 1] = fmaf(S[i * 4 + 1], d4.y, fmaf(vv, k4.y, sa * b4.y));
        o1 = fmaf(S[i * 4 + 1], r4.y, o1);
        S[i * 4 + 2] = fmaf(S[i * 4 + 2], d4.z, fmaf(vv, k4.z, sa * b4.z));
        o2 = fmaf(S[i * 4 + 2], r4.z, o2);
        S[i * 4 + 3] = fmaf(S[i * 4 + 3], d4.w, fmaf(vv, k4.w, sa * b4.w));
        o3 = fmaf(S[i * 4 + 3], r4.w, o3);
      }
      float oo = (o0 + o1) + (o2 + o3);
      oo = dppadd<0xB1>(oo);
      oo = dppadd<0x4E>(oo);
      if (cq == 0) o[base + (size_t)(c * CS + s) * Cc + row] = oo;
    }
    #undef LOADOPS
  }
  #undef LOADC
}

// ---------------- K6: head GroupNorm + rk bonus + gate ----------------
__global__ __launch_bounds__(256) void k6_out(
    const float* __restrict__ o, const float* __restrict__ r, const float* __restrict__ k,
    const float* __restrict__ v, const float* __restrict__ rk,
    const float* __restrict__ gnw, const float* __restrict__ gnb,
    const float* __restrict__ g, unsigned short* __restrict__ og) {
  const int row = blockIdx.x, tid = threadIdx.x;
  const int c = tid * 4;
  const size_t base = (size_t)row * Cc + c;
  float o0 = o[base], o1 = o[base + 1], o2 = o[base + 2], o3 = o[base + 3];
  float r0 = r[base], r1 = r[base + 1], r2 = r[base + 2], r3 = r[base + 3];
  float k0 = k[base], k1 = k[base + 1], k2 = k[base + 2], k3 = k[base + 3];
  float s = o0 + o1 + o2 + o3;
  float q = o0 * o0 + o1 * o1 + o2 * o2 + o3 * o3;
  float bs = r0 * k0 * rk[c] + r1 * k1 * rk[c + 1] + r2 * k2 * rk[c + 2] + r3 * k3 * rk[c + 3];
  #pragma unroll
  for (int m = 8; m; m >>= 1) {
    s += __shfl_xor(s, m); q += __shfl_xor(q, m); bs += __shfl_xor(bs, m);
  }
  float mu = s * (1.f / 64.f);
  float var = q * (1.f / 64.f) - mu * mu;
  float rs = rsqrtf(var + 64e-5f);
  float v0 = v[base], v1 = v[base + 1], v2 = v[base + 2], v3 = v[base + 3];
  float z0 = (o0 - mu) * rs * gnw[c] + gnb[c] + bs * v0;
  float z1 = (o1 - mu) * rs * gnw[c + 1] + gnb[c + 1] + bs * v1;
  float z2 = (o2 - mu) * rs * gnw[c + 2] + gnb[c + 2] + bs * v2;
  float z3 = (o3 - mu) * rs * gnw[c + 3] + gnb[c + 3] + bs * v3;
  ushort4 u;
  u.x = f2bf(z0 * g[base]); u.y = f2bf(z1 * g[base + 1]);
  u.z = f2bf(z2 * g[base + 2]); u.w = f2bf(z3 * g[base + 3]);
  *(ushort4*)(og + base) = u;
}

// ---------------- K8: FFN LN + time-shift mix ----------------
__global__ __launch_bounds__(256) void k8_ffnmix(
    const float* __restrict__ x2, const float* __restrict__ lnw, const float* __restrict__ lnb,
    const float* __restrict__ fxk, unsigned short* __restrict__ kf) {
  __shared__ float red[8];
  const int row = blockIdx.x;
  const int t = row & (Tt - 1);
  const int tid = threadIdx.x;
  const int c = tid * 4;
  const size_t base = (size_t)row * Cc + c;
  float a0 = x2[base], a1 = x2[base + 1], a2 = x2[base + 2], a3 = x2[base + 3];
  float mu, rs;
  row_stats(a0, a1, a2, a3, red, mu, rs, 1e-5f);
  float w0 = lnw[c], w1 = lnw[c + 1], w2 = lnw[c + 2], w3 = lnw[c + 3];
  float b0 = lnb[c], b1 = lnb[c + 1], b2 = lnb[c + 2], b3 = lnb[c + 3];
  float f0 = (a0 - mu) * rs * w0 + b0, f1 = (a1 - mu) * rs * w1 + b1;
  float f2 = (a2 - mu) * rs * w2 + b2, f3 = (a3 - mu) * rs * w3 + b3;
  float p0 = 0.f, p1 = 0.f, p2 = 0.f, p3 = 0.f;
  if (t > 0) {
    const size_t pb_ = base - Cc;
    float q0 = x2[pb_], q1 = x2[pb_ + 1], q2 = x2[pb_ + 2], q3 = x2[pb_ + 3];
    row_stats(q0, q1, q2, q3, red, mu, rs, 1e-5f);
    p0 = (q0 - mu) * rs * w0 + b0; p1 = (q1 - mu) * rs * w1 + b1;
    p2 = (q2 - mu) * rs * w2 + b2; p3 = (q3 - mu) * rs * w3 + b3;
  }
  ushort4 u;
  u.x = f2bf(f0 + (p0 - f0) * fxk[c]);
  u.y = f2bf(f1 + (p1 - f1) * fxk[c + 1]);
  u.z = f2bf(f2 + (p2 - f2) * fxk[c + 2]);
  u.w = f2bf(f3 + (p3 - f3) * fxk[c + 3]);
  *(ushort4*)(kf + base) = u;
}

// ---------------- host ----------------
extern "C" void kernel_launch(void* const* d_in, const int* in_sizes, int n_in,
                              void* d_out, int out_size, void* d_ws, size_t ws_size,
                              hipStream_t stream) {
  (void)in_sizes; (void)n_in; (void)out_size; (void)ws_size;
  const float* x    = (const float*)d_in[0];
  const float* lnpw = (const float*)d_in[2];
  const float* lnpb = (const float*)d_in[3];
  const float* lnaw = (const float*)d_in[4];
  const float* lnab = (const float*)d_in[5];
  const float* lnfw = (const float*)d_in[6];
  const float* lnfb = (const float*)d_in[7];
  const float* cxr  = (const float*)d_in[8];
  const float* cxw  = (const float*)d_in[9];
  const float* cxk  = (const float*)d_in[10];
  const float* cxv  = (const float*)d_in[11];
  const float* cxa  = (const float*)d_in[12];
  const float* cxg  = (const float*)d_in[13];
  const float* w0v  = (const float*)d_in[14];
  const float* w1m  = (const float*)d_in[15];
  const float* w2m  = (const float*)d_in[16];
  const float* a0v  = (const float*)d_in[17];
  const float* a1m  = (const float*)d_in[18];
  const float* a2m  = (const float*)d_in[19];
  const float* g1m  = (const float*)d_in[20];
  const float* g2m  = (const float*)d_in[21];
  const float* kkv  = (const float*)d_in[22];
  const float* kav  = (const float*)d_in[23];
  const float* rkv  = (const float*)d_in[24];
  const float* Wr   = (const float*)d_in[25];
  const float* Wk   = (const float*)d_in[26];
  const float* Wv   = (const float*)d_in[27];
  const float* Wo   = (const float*)d_in[28];
  const float* gnw  = (const float*)d_in[29];
  const float* gnb  = (const float*)d_in[30];
  const float* fxk  = (const float*)d_in[31];
  const float* Wf1  = (const float*)d_in[32];
  const float* Wf2  = (const float*)d_in[33];

  char* ws = (char*)d_ws;
  float* outx = (float*)d_out;          // final x (B,T,C)
  float* vout = outx + BTC;             // v_first = v (B,T,C)

  // workspace layout (aliases noted)
  size_t off = 0;
  unsigned short* WrT  = (unsigned short*)(ws + off); off += 2097152;
  unsigned short* WkT  = (unsigned short*)(ws + off); off += 2097152;
  unsigned short* WvT  = (unsigned short*)(ws + off); off += 2097152;
  unsigned short* WoT  = (unsigned short*)(ws + off); off += 2097152;
  unsigned short* Wf1T = (unsigned short*)(ws + off); off += 8388608;
  unsigned short* Wf2T = (unsigned short*)(ws + off); off += 8388608;
  unsigned short* w1T  = (unsigned short*)(ws + off); off += 131072;
  unsigned short* w2T  = (unsigned short*)(ws + off); off += 131072;
  unsigned short* a1T  = (unsigned short*)(ws + off); off += 131072;
  unsigned short* a2T  = (unsigned short*)(ws + off); off += 131072;
  unsigned short* g1T  = (unsigned short*)(ws + off); off += 262144;
  unsigned short* g2T  = (unsigned short*)(ws + off); off += 262144;
  float* xln = (float*)(ws + off); off += 16777216;
  unsigned short* mixR = (unsigned short*)(ws + off);          // 6 x 8388608
  unsigned short* mixW = (unsigned short*)(ws + off + 8388608);
  unsigned short* mixK = (unsigned short*)(ws + off + 16777216);
  unsigned short* mixV = (unsigned short*)(ws + off + 25165824);
  unsigned short* mixA = (unsigned short*)(ws + off + 33554432);
  unsigned short* mixG = (unsigned short*)(ws + off + 41943040);
  unsigned short* hbuf = (unsigned short*)(ws + off);          // alias mix (dead by then)
  off += 50331648;
  unsigned short* tmpw = (unsigned short*)(ws + off); off += 524288;
  unsigned short* tmpa = (unsigned short*)(ws + off); off += 524288;
  unsigned short* tmpg = (unsigned short*)(ws + off); off += 1048576;
  float* decay = (float*)(ws + off);
  unsigned short* og = (unsigned short*)(ws + off);            // alias decay (dead after K5)
  off += 16777216;
  float* aicl = (float*)(ws + off);
  float* obuf = (float*)(ws + off);                            // alias aicl (dead after K4)
  off += 16777216;
  float* gout = (float*)(ws + off); off += 16777216;
  float* rbuf = (float*)(ws + off);
  float* x2   = (float*)(ws + off);                            // alias rbuf (dead after K6)
  off += 16777216;
  float* kbuf = (float*)(ws + off); off += 16777216;
  float* awb  = (float*)(ws + off);
  unsigned short* kf = (unsigned short*)(ws + off);            // alias awb (dead after K5)
  off += 16777216;
  float* bwb  = (float*)(ws + off); off += 16777216;           // total ~187 MB

  dim3 tb(32, 8);
  // weight prep: f32 (K,N) -> bf16 (N,K)
  kt_transpose4<<<dim3(32, 32, 4), tb, 0, stream>>>(Wr, Wk, Wv, Wo, WrT, WkT, WvT, WoT);
  kt_transpose<<<dim3(128, 32), tb, 0, stream>>>(Wf1, Wf1T, 1024, 4096);
  kt_transpose<<<dim3(32, 128), tb, 0, stream>>>(Wf2, Wf2T, 4096, 1024);
  kt_transpose<<<dim3(2, 32), tb, 0, stream>>>(w1m, w1T, 1024, 64);
  kt_transpose<<<dim3(32, 2), tb, 0, stream>>>(w2m, w2T, 64, 1024);
  kt_transpose<<<dim3(2, 32), tb, 0, stream>>>(a1m, a1T, 1024, 64);
  kt_transpose<<<dim3(32, 2), tb, 0, stream>>>(a2m, a2T, 64, 1024);
  kt_transpose<<<dim3(4, 32), tb, 0, stream>>>(g1m, g1T, 1024, 128);
  kt_transpose<<<dim3(32, 4), tb, 0, stream>>>(g2m, g2T, 128, 1024);

  // K1: pre-LN + attn-LN + shift mixes
  k1_mix<<<Mm, 256, 0, stream>>>(x, lnpw, lnpb, lnaw, lnab, cxr, cxw, cxk, cxv, cxa, cxg,
                                 xln, mixR, mixW, mixK, mixV, mixA, mixG);

  // LoRA chains (N-tile = 64 now)
  kg_gemm<2><<<dim3(1, 32), 256, 0, stream>>>(mixW, w1T, Mm, 64, 1024, nullptr, tmpw, nullptr, nullptr);
  kg_gemm<6><<<dim3(16, 32), 256, 0, stream>>>(tmpw, w2T, Mm, 1024, 64, decay, nullptr, w0v, nullptr);
  kg_gemm<1><<<dim3(1, 32), 256, 0, stream>>>(mixA, a1T, Mm, 64, 1024, nullptr, tmpa, nullptr, nullptr);
  kg_gemm<5><<<dim3(16, 32), 256, 0, stream>>>(tmpa, a2T, Mm, 1024, 64, aicl, nullptr, a0v, nullptr);
  kg_gemm<3><<<dim3(2, 32), 256, 0, stream>>>(mixG, g1T, Mm, 128, 1024, nullptr, tmpg, nullptr, nullptr);
  kg_gemm<0><<<dim3(16, 32), 256, 0, stream>>>(tmpg, g2T, Mm, 1024, 128, gout, nullptr, nullptr, nullptr);

  // r / k / v projections (v straight into d_out as v_first)
  kg_gemm<0><<<dim3(16, 32), 256, 0, stream>>>(mixR, WrT, Mm, 1024, 1024, rbuf, nullptr, nullptr, nullptr);
  kg_gemm<0><<<dim3(16, 32), 256, 0, stream>>>(mixK, WkT, Mm, 1024, 1024, kbuf, nullptr, nullptr, nullptr);
  kg_gemm<0><<<dim3(16, 32), 256, 0, stream>>>(mixV, WvT, Mm, 1024, 1024, vout, nullptr, nullptr, nullptr);

  // recurrence inputs
  k4_prep<<<Mm, 256, 0, stream>>>(kbuf, aicl, kkv, kav, awb, bwb);
  // WKV7 scan
  k5_wkv7<<<512, 64, 0, stream>>>(rbuf, decay, kbuf, vout, awb, bwb, obuf);
  // GN + bonus + gate
  k6_out<<<Mm, 256, 0, stream>>>(obuf, rbuf, kbuf, vout, rkv, gnw, gnb, gout, og);
  // o-projection + residual -> x2
  kg_gemm<7><<<dim3(16, 32), 256, 0, stream>>>(og, WoT, Mm, 1024, 1024, x2, nullptr, nullptr, xln);
  // FFN
  k8_ffnmix<<<Mm, 256, 0, stream>>>(x2, lnfw, lnfb, fxk, kf);
  kg_gemm<4><<<dim3(64, 32), 256, 0, stream>>>(kf, Wf1T, Mm, 4096, 1024, nullptr, hbuf, nullptr, nullptr);
  kg_gemm<7><<<dim3(16, 32), 256, 0, stream>>>(hbuf, Wf2T, Mm, 1024, 4096, outx, nullptr, nullptr, x2);
}